// Round 16
// baseline (697.244 us; speedup 1.0000x reference)
//
#include <hip/hip_runtime.h>
#include <stdint.h>

#define NN 384
#define NE 3456
#define NLb 32
#define F 64
#define KD 32

typedef short shortx8 __attribute__((ext_vector_type(8)));
typedef float floatx4 __attribute__((ext_vector_type(4)));

__device__ __forceinline__ float sigm(float v) { return 1.0f / (1.0f + __expf(-v)); }
__device__ __forceinline__ float tanhf_(float v) {
    float x = fminf(fmaxf(v, -15.0f), 15.0f);
    float e = __expf(2.0f * x);
    return (e - 1.0f) / (e + 1.0f);
}
__device__ __forceinline__ uint16_t f2bf(float f) {
    uint32_t u = __float_as_uint(f);
    uint32_t r = (u + 0x7fffu + ((u >> 16) & 1u)) >> 16;
    return (uint16_t)r;
}
__device__ __forceinline__ float bf2f(uint16_t h) {
    return __uint_as_float((uint32_t)h << 16);
}
__device__ __forceinline__ uint32_t packhl(float v) {
    uint16_t h = f2bf(v);
    uint16_t l = f2bf(v - bf2f(h));
    return ((uint32_t)h << 16) | (uint32_t)l;
}
__device__ __forceinline__ float unpackhl(uint32_t u) {
    return __uint_as_float(u & 0xffff0000u) + __uint_as_float(u << 16);
}

__global__ void k_zero(float* p, int n) {
    int i = blockIdx.x * 256 + threadIdx.x;
    int st = gridDim.x * 256;
    for (; i < n; i += st) p[i] = 0.0f;
}

__global__ void k_build(const int* __restrict__ e1, const int* __restrict__ e2,
                        float* __restrict__ C, float* __restrict__ Adj) {
    int t = blockIdx.x * 256 + threadIdx.x;
    if (t >= 2 * NE) return;
    int g = t / NE, e = t % NE;
    const int* ei = g ? e2 : e1;
    int s = ei[e], d = ei[NE + e];
    atomicAdd(&C[(size_t)g * NN * NN + d * NN + s], 1.0f);
    if (e < NE - NN) Adj[(size_t)g * NN * NN + s * NN + d] = 1.0f;
}

__global__ void k_degx(const float* __restrict__ f1, const float* __restrict__ f2,
                       const float* __restrict__ Adj, float* __restrict__ X) {
    int g = blockIdx.y;
    int s = blockIdx.x * 64 + threadIdx.x;
    const float* feats = g ? f2 : f1;
    const float* A = Adj + (size_t)g * NN * NN;
    float* Xg = X + (size_t)g * NN * 33;
    float deg = 0.0f;
    for (int d = 0; d < NN; d++) deg += A[s * NN + d];
    for (int c = 0; c < NLb; c++) Xg[s * 33 + c] = feats[s * NLb + c];
    Xg[s * 33 + 32] = deg;
}

// lin0 row + inline hi/lo bf16 for HS slot 0
__global__ __launch_bounds__(64)
void k_lin0(const float* __restrict__ X, const float* __restrict__ w1,
            const float* __restrict__ b1, const float* __restrict__ w2,
            const float* __restrict__ b2, float* __restrict__ HS,
            uint16_t* __restrict__ hhi, uint16_t* __restrict__ hlo) {
    __shared__ float tl[64];
    int g = blockIdx.y, m = blockIdx.x, n = threadIdx.x;
    const float* Xr = X + (size_t)g * NN * 33 + m * 33;
    float t = b1[n];
#pragma unroll
    for (int k = 0; k < 33; k++) t += Xr[k] * w1[k * F + n];
    t = fmaxf(t, 0.0f);
    tl[n] = t;
    __syncthreads();
    float o = b2[n];
#pragma unroll 4
    for (int k = 0; k < F; k++) o += tl[k] * w2[k * F + n];
    size_t idx = (size_t)g * (6 * NN * F) + m * F + n;
    HS[idx] = o;
    uint16_t hh = f2bf(o);
    hhi[idx] = hh;
    hlo[idx] = f2bf(o - bf2f(hh));
}

// GIN layer row (z agg + MLP) + column-stat atomics for BN
__global__ __launch_bounds__(64)
void k_gin(const float* __restrict__ C, const float* __restrict__ hin, int hGs,
           const float* __restrict__ gw1, const float* __restrict__ gb1,
           const float* __restrict__ gw2, const float* __restrict__ gb2,
           const float* __restrict__ geps, int li,
           float* __restrict__ zout, int oGs, float* __restrict__ stats) {
    __shared__ float zl[64], tl[64];
    int g = blockIdx.y, m = blockIdx.x, n = threadIdx.x;
    const float* Crow = C + (size_t)g * NN * NN + (size_t)m * NN;
    const float* h = hin + (size_t)g * hGs;
    float acc = 0.0f;
#pragma unroll 4
    for (int k = 0; k < NN; k++) acc += Crow[k] * h[k * F + n];
    acc += (1.0f + geps[li]) * h[m * F + n];
    zl[n] = acc;
    __syncthreads();
    const float* W1 = gw1 + (size_t)li * F * F;
    const float* W2 = gw2 + (size_t)li * F * F;
    float t = gb1[li * F + n];
#pragma unroll 4
    for (int k = 0; k < F; k++) t += zl[k] * W1[k * F + n];
    t = fmaxf(t, 0.0f);
    tl[n] = t;
    __syncthreads();
    float o = gb2[li * F + n];
#pragma unroll 4
    for (int k = 0; k < F; k++) o += tl[k] * W2[k * F + n];
    zout[(size_t)g * oGs + m * F + n] = o;
    float* st = stats + li * 256 + g * 128;
    atomicAdd(&st[n], o);
    atomicAdd(&st[64 + n], o * o);
}

// BN apply (batch stats from k_gin atomics) + relu->H + hi/lo bf16 for HS slot
__global__ __launch_bounds__(256)
void k_bnapply(float* __restrict__ hsb, int hsGs, float* __restrict__ hbuf, int hGs,
               const float* __restrict__ gamma, const float* __restrict__ beta,
               const float* __restrict__ stats, int li,
               uint16_t* __restrict__ hhi, uint16_t* __restrict__ hlo, int slotOff) {
    int g = blockIdx.y;
    int base = (blockIdx.x * 256 + threadIdx.x) * 8;   // grid.x=12 -> covers 24576
    float* z = hsb + (size_t)g * hsGs;
    float* h = hbuf + (size_t)g * hGs;
    const float* st = stats + li * 256 + g * 128;
    int c0 = base & 63;
#pragma unroll
    for (int q = 0; q < 8; q++) {
        int idx = base + q;
        int c = c0 + q;
        float mu = st[c] * (1.0f / NN);
        float var = st[64 + c] * (1.0f / NN) - mu * mu;
        float is = rsqrtf(var + 1e-5f);
        float zn = (z[idx] - mu) * is * gamma[c] + beta[c];
        z[idx] = zn;
        h[idx] = fmaxf(zn, 0.0f);
        size_t hidx = (size_t)g * (6 * NN * F) + slotOff + idx;
        uint16_t hh = f2bf(zn);
        hhi[hidx] = hh;
        hlo[hidx] = f2bf(zn - bf2f(hh));
    }
}

__global__ __launch_bounds__(64)
void k_gedT2(const float* __restrict__ ged, uint16_t* __restrict__ ghi,
             uint16_t* __restrict__ glo) {
    __shared__ float t[64 * 65];
    int lk = blockIdx.x, lane = threadIdx.x;
    const float* src = ged + (size_t)lk * 4096;
    for (int d = 0; d < 64; d++) t[lane * 65 + d] = src[d * 64 + lane];
    __syncthreads();
    for (int e = 0; e < 64; e++) {
        float v = t[e * 65 + lane];
        uint16_t h = f2bf(v);
        ghi[(size_t)lk * 4096 + e * 64 + lane] = h;
        glo[(size_t)lk * 4096 + e * 64 + lane] = f2bf(v - bf2f(h));
    }
}

// Fragment-linear weight pack (u16) + biases (f32) — verified r11.
__global__ __launch_bounds__(256)
void k_wprep5(const float* __restrict__ wih, const float* __restrict__ whh,
              const float* __restrict__ waw, const float* __restrict__ vw,
              const float* __restrict__ bih, const float* __restrict__ bhh,
              const float* __restrict__ wab, const float* __restrict__ vat,
              const float* __restrict__ vb,
              uint16_t* __restrict__ wpk, float* __restrict__ wpb) {
    int t = threadIdx.x;
    for (int d = t; d < 3072; d += 256) {
        int c = d >> 9, L = (d >> 3) & 63, tt = d & 7;
        int src = (c * 16 + (L & 15)) * 32 + (L >> 4) * 8 + tt;
        float vi = wih[src]; uint16_t hi = f2bf(vi);
        wpk[d] = hi; wpk[3072 + d] = f2bf(vi - bf2f(hi));
        float vh = whh[src]; uint16_t hh = f2bf(vh);
        wpk[6144 + d] = hh; wpk[9216 + d] = f2bf(vh - bf2f(hh));
    }
    for (int d = t; d < 1024; d += 256) {
        int c = d >> 9, L = (d >> 3) & 63, tt = d & 7;
        int row = c * 16 + (L & 15), col = (L >> 4) * 8 + tt;
        float va = waw[col * 32 + row]; uint16_t ha = f2bf(va);
        wpk[12288 + d] = ha; wpk[13312 + d] = f2bf(va - bf2f(ha));
        float vv2 = vw[col * 32 + row]; uint16_t hv = f2bf(vv2);
        wpk[14336 + d] = hv; wpk[15360 + d] = f2bf(vv2 - bf2f(hv));
    }
    if (t < 32) {
        wpb[t]       = bih[t] + bhh[t];
        wpb[32 + t]  = bih[32 + t] + bhh[32 + t];
        wpb[64 + t]  = bih[64 + t];
        wpb[96 + t]  = bhh[64 + t];
        wpb[128 + t] = wab[t];
        wpb[160 + t] = vat[t];
        wpb[192 + t] = vb[t];
    }
}

// T1[l,i,n=k*64+e] hi/lo bf16 = sum_d gedT[l,n,d]*h1[l,i,d]  (verified r3+)
__global__ __launch_bounds__(256)
void k_t1m2(const uint16_t* __restrict__ gThi, const uint16_t* __restrict__ gTlo,
            const uint16_t* __restrict__ hbhi, const uint16_t* __restrict__ hblo,
            uint16_t* __restrict__ T1hi, uint16_t* __restrict__ T1lo) {
    int l = blockIdx.z;
    int w = threadIdx.x >> 6, lane = threadIdx.x & 63;
    int nb = blockIdx.x * 128 + (w >> 1) * 64;
    int ib = blockIdx.y * 128 + (w & 1) * 64;
    int lr = lane & 15, lq = lane >> 4;
    const uint16_t* gah = gThi + (size_t)l * 2048 * 64;
    const uint16_t* gal = gTlo + (size_t)l * 2048 * 64;
    const uint16_t* gbh = hbhi + (size_t)l * NN * F;
    const uint16_t* gbl = hblo + (size_t)l * NN * F;
    shortx8 Ah[4][2], Al[4][2];
#pragma unroll
    for (int s = 0; s < 4; s++)
#pragma unroll
        for (int ks = 0; ks < 2; ks++) {
            size_t off = (size_t)(nb + s * 16 + lr) * 64 + ks * 32 + lq * 8;
            Ah[s][ks] = *reinterpret_cast<const shortx8*>(gah + off);
            Al[s][ks] = *reinterpret_cast<const shortx8*>(gal + off);
        }
#pragma unroll
    for (int si = 0; si < 4; si++) {
        shortx8 Bh[2], Bl[2];
#pragma unroll
        for (int ks = 0; ks < 2; ks++) {
            size_t off = (size_t)(ib + si * 16 + lr) * 64 + ks * 32 + lq * 8;
            Bh[ks] = *reinterpret_cast<const shortx8*>(gbh + off);
            Bl[ks] = *reinterpret_cast<const shortx8*>(gbl + off);
        }
#pragma unroll
        for (int sn = 0; sn < 4; sn++) {
            floatx4 a = (floatx4){0.f, 0.f, 0.f, 0.f};
#pragma unroll
            for (int ks = 0; ks < 2; ks++) {
                a = __builtin_amdgcn_mfma_f32_16x16x32_bf16(Ah[sn][ks], Bh[ks], a, 0, 0, 0);
                a = __builtin_amdgcn_mfma_f32_16x16x32_bf16(Ah[sn][ks], Bl[ks], a, 0, 0, 0);
                a = __builtin_amdgcn_mfma_f32_16x16x32_bf16(Al[sn][ks], Bh[ks], a, 0, 0, 0);
            }
            size_t addr = ((size_t)l * NN + (ib + si * 16 + lr)) * 2048 + (nb + sn * 16 + lq * 4);
            uint2 hv, lv;
            uint16_t h0 = f2bf(a[0]), h1 = f2bf(a[1]), h2 = f2bf(a[2]), h3 = f2bf(a[3]);
            hv.x = (uint32_t)h0 | ((uint32_t)h1 << 16);
            hv.y = (uint32_t)h2 | ((uint32_t)h3 << 16);
            uint16_t l0 = f2bf(a[0] - bf2f(h0)), l1 = f2bf(a[1] - bf2f(h1));
            uint16_t l2 = f2bf(a[2] - bf2f(h2)), l3 = f2bf(a[3] - bf2f(h3));
            lv.x = (uint32_t)l0 | ((uint32_t)l1 << 16);
            lv.y = (uint32_t)l2 | ((uint32_t)l3 << 16);
            *reinterpret_cast<uint2*>(T1hi + addr) = hv;
            *reinterpret_cast<uint2*>(T1lo + addr) = lv;
        }
    }
}

#define WF(OFF, CC) (*reinterpret_cast<const shortx8*>(wl + (OFF) + (CC) * 512 + lane * 8))

// build hi/lo bf16 A-frag from mt-scratch SCR (rows=lr, k=lq*8+t, stride 36)
#define BUILD_AF(H8, L8, SCR) do {                                             \
    _Pragma("unroll") for (int t = 0; t < 8; t++) {                            \
        float fv = (SCR)[lr * 36 + lq * 8 + t];                                \
        uint16_t hc = f2bf(fv);                                                \
        H8[t] = (short)hc;                                                     \
        L8[t] = (short)f2bf(fv - bf2f(hc));                                    \
    }                                                                          \
} while (0)

// mega15 (verified r15): MFMA GRU/attn, per-mt 2-slot scratch, double-buffered
// T1 staging (1 barrier/layer), phase-B x from global spill.
__global__ __launch_bounds__(192, 1)
void k_mega15(const uint16_t* __restrict__ T1hi, const uint16_t* __restrict__ T1lo,
              const uint16_t* __restrict__ hbhi, const uint16_t* __restrict__ hblo,
              const uint16_t* __restrict__ wpk, const float* __restrict__ wpb,
              const float* __restrict__ q1w, const float* __restrict__ q1b,
              const float* __restrict__ q2w, const float* __restrict__ q2b,
              const float* __restrict__ kw, const float* __restrict__ kb,
              uint32_t* __restrict__ xspill, float* __restrict__ out) {
    __shared__ uint16_t wl[16384];
    __shared__ float wb[224];
    __shared__ uint16_t t1h[2][2048], t1l[2][2048];
    __shared__ float scr_all[3 * 2 * 580];
    const int TX = threadIdx.x;
    const int i = blockIdx.x >> 1;
    const int w = TX >> 6, lane = TX & 63, lr = lane & 15, lq = lane >> 4;
    const int j0w = (blockIdx.x & 1) * 192 + w * 64;
    float* scrw = scr_all + w * 2 * 580;

    {
        uint32_t* wl32 = reinterpret_cast<uint32_t*>(wl);
        const uint32_t* src32 = reinterpret_cast<const uint32_t*>(wpk);
        for (int d = TX; d < 8192; d += 192) wl32[d] = src32[d];
        for (int d = TX; d < 224; d += 192) wb[d] = wpb[d];
    }

#define STAGE_T1(LL, BUF) do {                                                 \
    const uint32_t* sh = reinterpret_cast<const uint32_t*>(                    \
        T1hi + ((size_t)(LL) * NN + i) * 2048);                                \
    const uint32_t* sl = reinterpret_cast<const uint32_t*>(                    \
        T1lo + ((size_t)(LL) * NN + i) * 2048);                                \
    uint32_t* dh = reinterpret_cast<uint32_t*>(t1h[BUF]);                      \
    uint32_t* dl = reinterpret_cast<uint32_t*>(t1l[BUF]);                      \
    for (int d = TX; d < 1024; d += 192) {                                     \
        int kk = d >> 5, ee = (d & 31) * 2;                                    \
        int du = ((((kk >> 4) * 2 + (ee >> 5)) * 512 +                         \
                   (((ee >> 3) & 3) * 16 + (kk & 15)) * 8 + (ee & 7)) >> 1);   \
        dh[du] = sh[d]; dl[du] = sl[d];                                        \
    }                                                                          \
} while (0)

#define X_TILE(LL, MT, CUR, SCR) do {                                          \
    shortx8 Bh[2], Bl[2];                                                      \
    _Pragma("unroll") for (int eh = 0; eh < 2; eh++) {                         \
        size_t boff = ((size_t)(6 + (LL)) * NN + (j0w + (MT) * 16 + lr)) * 64  \
                      + eh * 32 + lq * 8;                                      \
        Bh[eh] = *reinterpret_cast<const shortx8*>(hbhi + boff);               \
        Bl[eh] = *reinterpret_cast<const shortx8*>(hblo + boff);               \
    }                                                                          \
    uint32_t* xs = xspill + ((((size_t)blockIdx.x * 3 + w) * 6 + (LL)) * 4     \
                             + (MT)) * 512 + lane * 8;                         \
    _Pragma("unroll") for (int kt = 0; kt < 2; kt++) {                         \
        floatx4 a = (floatx4){0.f, 0.f, 0.f, 0.f};                             \
        _Pragma("unroll") for (int eh = 0; eh < 2; eh++) {                     \
            shortx8 Ah = *reinterpret_cast<const shortx8*>(                    \
                t1h[CUR] + (kt * 2 + eh) * 512 + lane * 8);                    \
            shortx8 Al = *reinterpret_cast<const shortx8*>(                    \
                t1l[CUR] + (kt * 2 + eh) * 512 + lane * 8);                    \
            a = __builtin_amdgcn_mfma_f32_16x16x32_bf16(Ah, Bh[eh], a, 0, 0, 0); \
            a = __builtin_amdgcn_mfma_f32_16x16x32_bf16(Ah, Bl[eh], a, 0, 0, 0); \
            a = __builtin_amdgcn_mfma_f32_16x16x32_bf16(Al, Bh[eh], a, 0, 0, 0); \
        }                                                                      \
        *reinterpret_cast<floatx4*>((SCR) + lr * 36 + kt * 16 + lq * 4) = a;   \
        uint4 uv;                                                              \
        uv.x = packhl(a[0]); uv.y = packhl(a[1]);                              \
        uv.z = packhl(a[2]); uv.w = packhl(a[3]);                              \
        *reinterpret_cast<uint4*>(xs + kt * 4) = uv;                           \
    }                                                                          \
} while (0)

    shortx8 hAh[4], hAl[4];
    float hC[4][2][4], pf[4][2][4], sdr[4][4];
#pragma unroll
    for (int mt = 0; mt < 4; mt++) {
#pragma unroll
        for (int t = 0; t < 8; t++) { hAh[mt][t] = 0; hAl[mt][t] = 0; }
#pragma unroll
        for (int g2 = 0; g2 < 2; g2++)
#pragma unroll
            for (int r = 0; r < 4; r++) { hC[mt][g2][r] = 0.0f; pf[mt][g2][r] = 0.0f; }
#pragma unroll
        for (int r = 0; r < 4; r++) sdr[mt][r] = 0.0f;
    }

    STAGE_T1(0, 0);
    __syncthreads();

    // ================= phase A: GRU + layer attention (MFMA) =================
#pragma unroll 1
    for (int l = 0; l < 6; l++) {
        const int cur = l & 1;
        if (l < 5) STAGE_T1(l + 1, cur ^ 1);
#pragma unroll
        for (int mt = 0; mt < 4; mt++) {
            float* scr = scrw + (mt & 1) * 580;
            X_TILE(l, mt, cur, scr);
            shortx8 xAh, xAl;
            BUILD_AF(xAh, xAl, scr);
            floatx4 aRZ[4], aIN[2], aHN[2];
#pragma unroll
            for (int gt = 0; gt < 4; gt++) {
                floatx4 a = (floatx4){0.f, 0.f, 0.f, 0.f};
                a = __builtin_amdgcn_mfma_f32_16x16x32_bf16(xAh, WF(0, gt), a, 0, 0, 0);
                a = __builtin_amdgcn_mfma_f32_16x16x32_bf16(xAh, WF(3072, gt), a, 0, 0, 0);
                a = __builtin_amdgcn_mfma_f32_16x16x32_bf16(xAl, WF(0, gt), a, 0, 0, 0);
                a = __builtin_amdgcn_mfma_f32_16x16x32_bf16(hAh[mt], WF(6144, gt), a, 0, 0, 0);
                a = __builtin_amdgcn_mfma_f32_16x16x32_bf16(hAh[mt], WF(9216, gt), a, 0, 0, 0);
                a = __builtin_amdgcn_mfma_f32_16x16x32_bf16(hAl[mt], WF(6144, gt), a, 0, 0, 0);
                aRZ[gt] = a;
            }
#pragma unroll
            for (int g2 = 0; g2 < 2; g2++) {
                floatx4 a = (floatx4){0.f, 0.f, 0.f, 0.f};
                a = __builtin_amdgcn_mfma_f32_16x16x32_bf16(xAh, WF(0, 4 + g2), a, 0, 0, 0);
                a = __builtin_amdgcn_mfma_f32_16x16x32_bf16(xAh, WF(3072, 4 + g2), a, 0, 0, 0);
                a = __builtin_amdgcn_mfma_f32_16x16x32_bf16(xAl, WF(0, 4 + g2), a, 0, 0, 0);
                aIN[g2] = a;
                floatx4 b = (floatx4){0.f, 0.f, 0.f, 0.f};
                b = __builtin_amdgcn_mfma_f32_16x16x32_bf16(hAh[mt], WF(6144, 4 + g2), b, 0, 0, 0);
                b = __builtin_amdgcn_mfma_f32_16x16x32_bf16(hAh[mt], WF(9216, 4 + g2), b, 0, 0, 0);
                b = __builtin_amdgcn_mfma_f32_16x16x32_bf16(hAl[mt], WF(6144, 4 + g2), b, 0, 0, 0);
                aHN[g2] = b;
            }
#pragma unroll
            for (int g2 = 0; g2 < 2; g2++)
#pragma unroll
                for (int r = 0; r < 4; r++) {
                    float rg = sigm(aRZ[g2][r] + wb[g2 * 16 + lr]);
                    float zg = sigm(aRZ[2 + g2][r] + wb[32 + g2 * 16 + lr]);
                    float ng = tanhf_(aIN[g2][r] + wb[64 + g2 * 16 + lr]
                                      + rg * (aHN[g2][r] + wb[96 + g2 * 16 + lr]));
                    hC[mt][g2][r] = (1.0f - zg) * ng + zg * hC[mt][g2][r];
                }
#pragma unroll
            for (int g2 = 0; g2 < 2; g2++)
#pragma unroll
                for (int r = 0; r < 4; r++)
                    scr[(4 * lq + r) * 36 + g2 * 16 + lr] = hC[mt][g2][r];
            BUILD_AF(hAh[mt], hAl[mt], scr);
            floatx4 tac[2];
#pragma unroll
            for (int ct = 0; ct < 2; ct++) {
                floatx4 a = (floatx4){0.f, 0.f, 0.f, 0.f};
                a = __builtin_amdgcn_mfma_f32_16x16x32_bf16(hAh[mt], WF(12288, ct), a, 0, 0, 0);
                a = __builtin_amdgcn_mfma_f32_16x16x32_bf16(hAh[mt], WF(13312, ct), a, 0, 0, 0);
                a = __builtin_amdgcn_mfma_f32_16x16x32_bf16(hAl[mt], WF(12288, ct), a, 0, 0, 0);
                tac[ct] = a;
            }
            float rs[4];
#pragma unroll
            for (int r = 0; r < 4; r++)
                rs[r] = tanhf_(tac[0][r] + wb[128 + lr]) * wb[160 + lr]
                      + tanhf_(tac[1][r] + wb[144 + lr]) * wb[176 + lr];
#pragma unroll
            for (int m = 1; m < 16; m <<= 1)
#pragma unroll
                for (int r = 0; r < 4; r++) rs[r] += __shfl_xor(rs[r], m, 64);
#pragma unroll
            for (int r = 0; r < 4; r++) {
                float en = __expf(rs[r]);
                sdr[mt][r] += en;
#pragma unroll
                for (int g2 = 0; g2 < 2; g2++)
                    pf[mt][g2][r] += en * hC[mt][g2][r];
            }
        }
        __syncthreads();
    }

    // ---------------- handoff: pattern -> per-thread, then q -> qk ----------------
    float patt[KD];
    {
#pragma unroll
        for (int mt = 0; mt < 4; mt++) {
            float* scr = scrw + (mt & 1) * 580;
#pragma unroll
            for (int g2 = 0; g2 < 2; g2++)
#pragma unroll
                for (int r = 0; r < 4; r++)
                    scr[(4 * lq + r) * 36 + g2 * 16 + lr] = pf[mt][g2][r];
#pragma unroll
            for (int r = 0; r < 4; r++)
                scr[(4 * lq + r) * 36 + 32] = sdr[mt][r];
            if ((lane >> 4) == mt) {
                float is = 1.0f / scr[(lane & 15) * 36 + 32];
#pragma unroll
                for (int k = 0; k < KD; k++) patt[k] = scr[(lane & 15) * 36 + k] * is;
            }
        }
    }
    float qk[KD], qd;
    {
        float t1r[KD];
#pragma unroll
        for (int c = 0; c < KD; c++) {
            float t = q1b[c];
#pragma unroll
            for (int k = 0; k < KD; k++) t += patt[k] * q1w[k * KD + c];
            t1r[c] = fmaxf(t, 0.0f);
        }
        float q[KD];
#pragma unroll
        for (int c = 0; c < KD; c++) {
            float t = q2b[c];
#pragma unroll
            for (int k = 0; k < KD; k++) t += t1r[k] * q2w[k * KD + c];
            q[c] = t;
        }
        qd = 0.0f;
#pragma unroll
        for (int c = 0; c < KD; c++) qd += q[c] * kb[c];
#pragma unroll
        for (int k = 0; k < KD; k++) {
            float t = 0.0f;
#pragma unroll
            for (int c = 0; c < KD; c++) t += q[c] * kw[k * KD + c];
            qk[k] = t;
        }
    }

    // ================= phase B: scores + context from spilled x =================
    float ctx[KD];
#pragma unroll
    for (int k = 0; k < KD; k++) ctx[k] = 0.0f;
    float s2m = -1e30f, s2d = 0.0f;
#pragma unroll 1
    for (int l = 0; l < 6; l++) {
        float eo = 1.0f, en = 0.0f;
#pragma unroll
        for (int mt = 0; mt < 4; mt++) {
            float* scr = scrw + (mt & 1) * 580;
            const uint32_t* xs = xspill + ((((size_t)blockIdx.x * 3 + w) * 6 + l) * 4
                                           + mt) * 512 + lane * 8;
            uint4 u0 = *reinterpret_cast<const uint4*>(xs);
            uint4 u1 = *reinterpret_cast<const uint4*>(xs + 4);
            floatx4 a0, a1;
            a0[0] = unpackhl(u0.x); a0[1] = unpackhl(u0.y);
            a0[2] = unpackhl(u0.z); a0[3] = unpackhl(u0.w);
            a1[0] = unpackhl(u1.x); a1[1] = unpackhl(u1.y);
            a1[2] = unpackhl(u1.z); a1[3] = unpackhl(u1.w);
            *reinterpret_cast<floatx4*>(scr + lr * 36 + 0 * 16 + lq * 4) = a0;
            *reinterpret_cast<floatx4*>(scr + lr * 36 + 1 * 16 + lq * 4) = a1;
            if ((lane >> 4) == mt) {
                float s = qd;
#pragma unroll
                for (int k = 0; k < KD; k++) s += scr[(lane & 15) * 36 + k] * qk[k];
                s *= 0.17677669529663687f;
                float nm = fmaxf(s2m, s);
                eo = __expf(s2m - nm); en = __expf(s - nm);
                s2d = s2d * eo + en; s2m = nm;
            }
            shortx8 xAh, xAl;
            BUILD_AF(xAh, xAl, scr);
#pragma unroll
            for (int ct = 0; ct < 2; ct++) {
                floatx4 a = (floatx4){0.f, 0.f, 0.f, 0.f};
                a = __builtin_amdgcn_mfma_f32_16x16x32_bf16(xAh, WF(14336, ct), a, 0, 0, 0);
                a = __builtin_amdgcn_mfma_f32_16x16x32_bf16(xAh, WF(15360, ct), a, 0, 0, 0);
                a = __builtin_amdgcn_mfma_f32_16x16x32_bf16(xAl, WF(14336, ct), a, 0, 0, 0);
#pragma unroll
                for (int r = 0; r < 4; r++)
                    scr[(4 * lq + r) * 36 + ct * 16 + lr] = a[r];
            }
            if ((lane >> 4) == mt) {
#pragma unroll
                for (int c = 0; c < KD; c++)
                    ctx[c] = ctx[c] * eo + en * (scr[(lane & 15) * 36 + c] + wb[192 + c]);
            }
        }
    }
    float invd = 1.0f / s2d;
    float* op = out + ((size_t)i * NN + j0w + lane) * KD;
#pragma unroll
    for (int k = 0; k < KD; k += 4) {
        float4 w4;
        w4.x = ctx[k] * invd; w4.y = ctx[k + 1] * invd;
        w4.z = ctx[k + 2] * invd; w4.w = ctx[k + 3] * invd;
        *reinterpret_cast<float4*>(op + k) = w4;
    }
#undef STAGE_T1
#undef X_TILE
}

extern "C" void kernel_launch(void* const* d_in, const int* in_sizes, int n_in,
                              void* d_out, int out_size, void* d_ws, size_t ws_size,
                              hipStream_t stream) {
    const float* f1   = (const float*)d_in[0];
    const float* f2   = (const float*)d_in[1];
    const float* l0w1 = (const float*)d_in[2];
    const float* l0b1 = (const float*)d_in[3];
    const float* l0w2 = (const float*)d_in[4];
    const float* l0b2 = (const float*)d_in[5];
    const float* geps = (const float*)d_in[6];
    const float* gw1  = (const float*)d_in[7];
    const float* gb1  = (const float*)d_in[8];
    const float* gw2  = (const float*)d_in[9];
    const float* gb2  = (const float*)d_in[10];
    const float* gga  = (const float*)d_in[11];
    const float* gbe  = (const float*)d_in[12];
    const float* ged  = (const float*)d_in[13];
    const float* wih  = (const float*)d_in[14];
    const float* whh  = (const float*)d_in[15];
    const float* bih  = (const float*)d_in[16];
    const float* bhh  = (const float*)d_in[17];
    const float* waw  = (const float*)d_in[18];
    const float* wab  = (const float*)d_in[19];
    const float* vat  = (const float*)d_in[20];
    const float* q1w  = (const float*)d_in[21];
    const float* q1b  = (const float*)d_in[22];
    const float* q2w  = (const float*)d_in[23];
    const float* q2b  = (const float*)d_in[24];
    const float* kw   = (const float*)d_in[25];
    const float* kb   = (const float*)d_in[26];
    const float* vw   = (const float*)d_in[27];
    const float* vb   = (const float*)d_in[28];
    const int*   e1   = (const int*)d_in[29];
    const int*   e2   = (const int*)d_in[30];

    // ---- workspace layout ----
    float* C       = (float*)d_ws;                       // 2*NN*NN
    float* Adj     = C + (size_t)2 * NN * NN;            // 2*NN*NN
    float* bnst    = Adj + (size_t)2 * NN * NN;          // 5*2*128 = 1280
    float* X       = bnst + 1280;                        // 2*NN*33
    float* H       = X + (size_t)2 * NN * 33;            // 2*NN*F
    float* HS      = H + (size_t)2 * NN * F;             // [2][6][NN][F]
    float* wpb     = HS + (size_t)2 * 6 * NN * F;        // 224 (+pad to 256)
    uint16_t* hbhi = (uint16_t*)(wpb + 256);             // [2][6][NN][F]
    uint16_t* hblo = hbhi + (size_t)2 * 6 * NN * F;
    uint16_t* gThi = hblo + (size_t)2 * 6 * NN * F;      // 6*2048*64
    uint16_t* gTlo = gThi + (size_t)6 * 2048 * 64;
    uint16_t* T1hi = gTlo + (size_t)6 * 2048 * 64;       // 6*NN*2048
    uint16_t* T1lo = T1hi + (size_t)6 * NN * 2048;
    uint16_t* wpk  = T1lo + (size_t)6 * NN * 2048;       // 16384
    uint32_t* xspill = (uint32_t*)(wpk + 16384);         // 768*3*6*4*512 u32 = 113 MB
    float* out = (float*)d_out;

    const int GHS = 6 * NN * F;
    const int GH  = NN * F;

    k_zero<<<576, 256, 0, stream>>>(C, 4 * NN * NN + 1280);
    k_build<<<(2 * NE + 255) / 256, 256, 0, stream>>>(e1, e2, C, Adj);
    k_degx<<<dim3(6, 2), 64, 0, stream>>>(f1, f2, Adj, X);
    k_lin0<<<dim3(NN, 2), 64, 0, stream>>>(X, l0w1, l0b1, l0w2, l0b2, HS, hbhi, hblo);
    for (int li = 0; li < 5; li++) {
        const float* hp = (li == 0) ? HS : H;
        int hGs = (li == 0) ? GHS : GH;
        k_gin<<<dim3(NN, 2), 64, 0, stream>>>(C, hp, hGs, gw1, gb1, gw2, gb2,
                                              geps, li, HS + (li + 1) * GH, GHS, bnst);
        k_bnapply<<<dim3(12, 2), 256, 0, stream>>>(HS + (li + 1) * GH, GHS, H, GH,
                                                   gga + li * F, gbe + li * F,
                                                   bnst, li, hbhi, hblo,
                                                   (li + 1) * GH);
    }
    k_gedT2<<<6 * KD, 64, 0, stream>>>(ged, gThi, gTlo);
    k_wprep5<<<1, 256, 0, stream>>>(wih, whh, waw, vw, bih, bhh, wab, vat, vb,
                                    wpk, wpb);
    k_t1m2<<<dim3(16, 3, 6), 256, 0, stream>>>(gThi, gTlo, hbhi, hblo, T1hi, T1lo);
    k_mega15<<<768, 192, 0, stream>>>(T1hi, T1lo, hbhi, hblo, wpk, wpb,
                                      q1w, q1b, q2w, q2b, kw, kb, xspill, out);
}

// Round 18
// 681.301 us; speedup vs baseline: 1.0234x; 1.0234x over previous
//
#include <hip/hip_runtime.h>
#include <stdint.h>

#define NN 384
#define NE 3456
#define NLb 32
#define F 64
#define KD 32

typedef short shortx8 __attribute__((ext_vector_type(8)));
typedef float floatx4 __attribute__((ext_vector_type(4)));

__device__ __forceinline__ float sigm(float v) { return 1.0f / (1.0f + __expf(-v)); }
__device__ __forceinline__ float tanhf_(float v) {
    float x = fminf(fmaxf(v, -15.0f), 15.0f);
    float e = __expf(2.0f * x);
    return (e - 1.0f) / (e + 1.0f);
}
__device__ __forceinline__ uint16_t f2bf(float f) {
    uint32_t u = __float_as_uint(f);
    uint32_t r = (u + 0x7fffu + ((u >> 16) & 1u)) >> 16;
    return (uint16_t)r;
}
__device__ __forceinline__ float bf2f(uint16_t h) {
    return __uint_as_float((uint32_t)h << 16);
}
__device__ __forceinline__ uint32_t packhl(float v) {
    uint16_t h = f2bf(v);
    uint16_t l = f2bf(v - bf2f(h));
    return ((uint32_t)h << 16) | (uint32_t)l;
}
__device__ __forceinline__ float unpackhl(uint32_t u) {
    return __uint_as_float(u & 0xffff0000u) + __uint_as_float(u << 16);
}

__global__ void k_zero(float* p, int n) {
    int i = blockIdx.x * 256 + threadIdx.x;
    int st = gridDim.x * 256;
    for (; i < n; i += st) p[i] = 0.0f;
}

__global__ void k_build(const int* __restrict__ e1, const int* __restrict__ e2,
                        float* __restrict__ C, float* __restrict__ Adj) {
    int t = blockIdx.x * 256 + threadIdx.x;
    if (t >= 2 * NE) return;
    int g = t / NE, e = t % NE;
    const int* ei = g ? e2 : e1;
    int s = ei[e], d = ei[NE + e];
    atomicAdd(&C[(size_t)g * NN * NN + d * NN + s], 1.0f);
    if (e < NE - NN) Adj[(size_t)g * NN * NN + s * NN + d] = 1.0f;
}

__global__ void k_degx(const float* __restrict__ f1, const float* __restrict__ f2,
                       const float* __restrict__ Adj, float* __restrict__ X) {
    int g = blockIdx.y;
    int s = blockIdx.x * 64 + threadIdx.x;
    const float* feats = g ? f2 : f1;
    const float* A = Adj + (size_t)g * NN * NN;
    float* Xg = X + (size_t)g * NN * 33;
    float deg = 0.0f;
    for (int d = 0; d < NN; d++) deg += A[s * NN + d];
    for (int c = 0; c < NLb; c++) Xg[s * 33 + c] = feats[s * NLb + c];
    Xg[s * 33 + 32] = deg;
}

// lin0 row + inline hi/lo bf16 for HS slot 0
__global__ __launch_bounds__(64)
void k_lin0(const float* __restrict__ X, const float* __restrict__ w1,
            const float* __restrict__ b1, const float* __restrict__ w2,
            const float* __restrict__ b2, float* __restrict__ HS,
            uint16_t* __restrict__ hhi, uint16_t* __restrict__ hlo) {
    __shared__ float tl[64];
    int g = blockIdx.y, m = blockIdx.x, n = threadIdx.x;
    const float* Xr = X + (size_t)g * NN * 33 + m * 33;
    float t = b1[n];
#pragma unroll
    for (int k = 0; k < 33; k++) t += Xr[k] * w1[k * F + n];
    t = fmaxf(t, 0.0f);
    tl[n] = t;
    __syncthreads();
    float o = b2[n];
#pragma unroll 4
    for (int k = 0; k < F; k++) o += tl[k] * w2[k * F + n];
    size_t idx = (size_t)g * (6 * NN * F) + m * F + n;
    HS[idx] = o;
    uint16_t hh = f2bf(o);
    hhi[idx] = hh;
    hlo[idx] = f2bf(o - bf2f(hh));
}

// GIN layer row (z agg + MLP) + column-stat atomics for BN
__global__ __launch_bounds__(64)
void k_gin(const float* __restrict__ C, const float* __restrict__ hin, int hGs,
           const float* __restrict__ gw1, const float* __restrict__ gb1,
           const float* __restrict__ gw2, const float* __restrict__ gb2,
           const float* __restrict__ geps, int li,
           float* __restrict__ zout, int oGs, float* __restrict__ stats) {
    __shared__ float zl[64], tl[64];
    int g = blockIdx.y, m = blockIdx.x, n = threadIdx.x;
    const float* Crow = C + (size_t)g * NN * NN + (size_t)m * NN;
    const float* h = hin + (size_t)g * hGs;
    float acc = 0.0f;
#pragma unroll 4
    for (int k = 0; k < NN; k++) acc += Crow[k] * h[k * F + n];
    acc += (1.0f + geps[li]) * h[m * F + n];
    zl[n] = acc;
    __syncthreads();
    const float* W1 = gw1 + (size_t)li * F * F;
    const float* W2 = gw2 + (size_t)li * F * F;
    float t = gb1[li * F + n];
#pragma unroll 4
    for (int k = 0; k < F; k++) t += zl[k] * W1[k * F + n];
    t = fmaxf(t, 0.0f);
    tl[n] = t;
    __syncthreads();
    float o = gb2[li * F + n];
#pragma unroll 4
    for (int k = 0; k < F; k++) o += tl[k] * W2[k * F + n];
    zout[(size_t)g * oGs + m * F + n] = o;
    float* st = stats + li * 256 + g * 128;
    atomicAdd(&st[n], o);
    atomicAdd(&st[64 + n], o * o);
}

// BN apply (batch stats from k_gin atomics) + relu->H + hi/lo bf16 for HS slot
__global__ __launch_bounds__(256)
void k_bnapply(float* __restrict__ hsb, int hsGs, float* __restrict__ hbuf, int hGs,
               const float* __restrict__ gamma, const float* __restrict__ beta,
               const float* __restrict__ stats, int li,
               uint16_t* __restrict__ hhi, uint16_t* __restrict__ hlo, int slotOff) {
    int g = blockIdx.y;
    int base = (blockIdx.x * 256 + threadIdx.x) * 8;
    float* z = hsb + (size_t)g * hsGs;
    float* h = hbuf + (size_t)g * hGs;
    const float* st = stats + li * 256 + g * 128;
    int c0 = base & 63;
#pragma unroll
    for (int q = 0; q < 8; q++) {
        int idx = base + q;
        int c = c0 + q;
        float mu = st[c] * (1.0f / NN);
        float var = st[64 + c] * (1.0f / NN) - mu * mu;
        float is = rsqrtf(var + 1e-5f);
        float zn = (z[idx] - mu) * is * gamma[c] + beta[c];
        z[idx] = zn;
        h[idx] = fmaxf(zn, 0.0f);
        size_t hidx = (size_t)g * (6 * NN * F) + slotOff + idx;
        uint16_t hh = f2bf(zn);
        hhi[hidx] = hh;
        hlo[hidx] = f2bf(zn - bf2f(hh));
    }
}

__global__ __launch_bounds__(64)
void k_gedT2(const float* __restrict__ ged, uint16_t* __restrict__ ghi,
             uint16_t* __restrict__ glo) {
    __shared__ float t[64 * 65];
    int lk = blockIdx.x, lane = threadIdx.x;
    const float* src = ged + (size_t)lk * 4096;
    for (int d = 0; d < 64; d++) t[lane * 65 + d] = src[d * 64 + lane];
    __syncthreads();
    for (int e = 0; e < 64; e++) {
        float v = t[e * 65 + lane];
        uint16_t h = f2bf(v);
        ghi[(size_t)lk * 4096 + e * 64 + lane] = h;
        glo[(size_t)lk * 4096 + e * 64 + lane] = f2bf(v - bf2f(h));
    }
}

// Fragment-linear weight pack (u16) + biases (f32) — verified r11.
__global__ __launch_bounds__(256)
void k_wprep5(const float* __restrict__ wih, const float* __restrict__ whh,
              const float* __restrict__ waw, const float* __restrict__ vw,
              const float* __restrict__ bih, const float* __restrict__ bhh,
              const float* __restrict__ wab, const float* __restrict__ vat,
              const float* __restrict__ vb,
              uint16_t* __restrict__ wpk, float* __restrict__ wpb) {
    int t = threadIdx.x;
    for (int d = t; d < 3072; d += 256) {
        int c = d >> 9, L = (d >> 3) & 63, tt = d & 7;
        int src = (c * 16 + (L & 15)) * 32 + (L >> 4) * 8 + tt;
        float vi = wih[src]; uint16_t hi = f2bf(vi);
        wpk[d] = hi; wpk[3072 + d] = f2bf(vi - bf2f(hi));
        float vh = whh[src]; uint16_t hh = f2bf(vh);
        wpk[6144 + d] = hh; wpk[9216 + d] = f2bf(vh - bf2f(hh));
    }
    for (int d = t; d < 1024; d += 256) {
        int c = d >> 9, L = (d >> 3) & 63, tt = d & 7;
        int row = c * 16 + (L & 15), col = (L >> 4) * 8 + tt;
        float va = waw[col * 32 + row]; uint16_t ha = f2bf(va);
        wpk[12288 + d] = ha; wpk[13312 + d] = f2bf(va - bf2f(ha));
        float vv2 = vw[col * 32 + row]; uint16_t hv = f2bf(vv2);
        wpk[14336 + d] = hv; wpk[15360 + d] = f2bf(vv2 - bf2f(hv));
    }
    if (t < 32) {
        wpb[t]       = bih[t] + bhh[t];
        wpb[32 + t]  = bih[32 + t] + bhh[32 + t];
        wpb[64 + t]  = bih[64 + t];
        wpb[96 + t]  = bhh[64 + t];
        wpb[128 + t] = wab[t];
        wpb[160 + t] = vat[t];
        wpb[192 + t] = vb[t];
    }
}

// T1[l,i,n=k*64+e] hi/lo bf16 = sum_d gedT[l,n,d]*h1[l,i,d]  (verified r3+)
__global__ __launch_bounds__(256)
void k_t1m2(const uint16_t* __restrict__ gThi, const uint16_t* __restrict__ gTlo,
            const uint16_t* __restrict__ hbhi, const uint16_t* __restrict__ hblo,
            uint16_t* __restrict__ T1hi, uint16_t* __restrict__ T1lo) {
    int l = blockIdx.z;
    int w = threadIdx.x >> 6, lane = threadIdx.x & 63;
    int nb = blockIdx.x * 128 + (w >> 1) * 64;
    int ib = blockIdx.y * 128 + (w & 1) * 64;
    int lr = lane & 15, lq = lane >> 4;
    const uint16_t* gah = gThi + (size_t)l * 2048 * 64;
    const uint16_t* gal = gTlo + (size_t)l * 2048 * 64;
    const uint16_t* gbh = hbhi + (size_t)l * NN * F;
    const uint16_t* gbl = hblo + (size_t)l * NN * F;
    shortx8 Ah[4][2], Al[4][2];
#pragma unroll
    for (int s = 0; s < 4; s++)
#pragma unroll
        for (int ks = 0; ks < 2; ks++) {
            size_t off = (size_t)(nb + s * 16 + lr) * 64 + ks * 32 + lq * 8;
            Ah[s][ks] = *reinterpret_cast<const shortx8*>(gah + off);
            Al[s][ks] = *reinterpret_cast<const shortx8*>(gal + off);
        }
#pragma unroll
    for (int si = 0; si < 4; si++) {
        shortx8 Bh[2], Bl[2];
#pragma unroll
        for (int ks = 0; ks < 2; ks++) {
            size_t off = (size_t)(ib + si * 16 + lr) * 64 + ks * 32 + lq * 8;
            Bh[ks] = *reinterpret_cast<const shortx8*>(gbh + off);
            Bl[ks] = *reinterpret_cast<const shortx8*>(gbl + off);
        }
#pragma unroll
        for (int sn = 0; sn < 4; sn++) {
            floatx4 a = (floatx4){0.f, 0.f, 0.f, 0.f};
#pragma unroll
            for (int ks = 0; ks < 2; ks++) {
                a = __builtin_amdgcn_mfma_f32_16x16x32_bf16(Ah[sn][ks], Bh[ks], a, 0, 0, 0);
                a = __builtin_amdgcn_mfma_f32_16x16x32_bf16(Ah[sn][ks], Bl[ks], a, 0, 0, 0);
                a = __builtin_amdgcn_mfma_f32_16x16x32_bf16(Al[sn][ks], Bh[ks], a, 0, 0, 0);
            }
            size_t addr = ((size_t)l * NN + (ib + si * 16 + lr)) * 2048 + (nb + sn * 16 + lq * 4);
            uint2 hv, lv;
            uint16_t h0 = f2bf(a[0]), h1 = f2bf(a[1]), h2 = f2bf(a[2]), h3 = f2bf(a[3]);
            hv.x = (uint32_t)h0 | ((uint32_t)h1 << 16);
            hv.y = (uint32_t)h2 | ((uint32_t)h3 << 16);
            uint16_t l0 = f2bf(a[0] - bf2f(h0)), l1 = f2bf(a[1] - bf2f(h1));
            uint16_t l2 = f2bf(a[2] - bf2f(h2)), l3 = f2bf(a[3] - bf2f(h3));
            lv.x = (uint32_t)l0 | ((uint32_t)l1 << 16);
            lv.y = (uint32_t)l2 | ((uint32_t)l3 << 16);
            *reinterpret_cast<uint2*>(T1hi + addr) = hv;
            *reinterpret_cast<uint2*>(T1lo + addr) = lv;
        }
    }
}

#define WF(OFF, CC) (*reinterpret_cast<const shortx8*>(wl + (OFF) + (CC) * 512 + lane * 8))

// build hi/lo bf16 A-frag from mt-scratch SCR (rows=lr, k=lq*8+t, stride 36)
#define BUILD_AF(H8, L8, SCR) do {                                             \
    _Pragma("unroll") for (int t = 0; t < 8; t++) {                            \
        float fv = (SCR)[lr * 36 + lq * 8 + t];                                \
        uint16_t hc = f2bf(fv);                                                \
        H8[t] = (short)hc;                                                     \
        L8[t] = (short)f2bf(fv - bf2f(hc));                                    \
    }                                                                          \
} while (0)

// mega15 (verified r15/r16): MFMA GRU/attn, per-mt 2-slot scratch, double-
// buffered T1 staging (1 barrier/layer), phase-B x from global spill.
__global__ __launch_bounds__(192, 1)
void k_mega15(const uint16_t* __restrict__ T1hi, const uint16_t* __restrict__ T1lo,
              const uint16_t* __restrict__ hbhi, const uint16_t* __restrict__ hblo,
              const uint16_t* __restrict__ wpk, const float* __restrict__ wpb,
              const float* __restrict__ q1w, const float* __restrict__ q1b,
              const float* __restrict__ q2w, const float* __restrict__ q2b,
              const float* __restrict__ kw, const float* __restrict__ kb,
              uint32_t* __restrict__ xspill, float* __restrict__ out) {
    __shared__ uint16_t wl[16384];
    __shared__ float wb[224];
    __shared__ uint16_t t1h[2][2048], t1l[2][2048];
    __shared__ float scr_all[3 * 2 * 580];
    const int TX = threadIdx.x;
    const int i = blockIdx.x >> 1;
    const int w = TX >> 6, lane = TX & 63, lr = lane & 15, lq = lane >> 4;
    const int j0w = (blockIdx.x & 1) * 192 + w * 64;
    float* scrw = scr_all + w * 2 * 580;

    {
        uint32_t* wl32 = reinterpret_cast<uint32_t*>(wl);
        const uint32_t* src32 = reinterpret_cast<const uint32_t*>(wpk);
        for (int d = TX; d < 8192; d += 192) wl32[d] = src32[d];
        for (int d = TX; d < 224; d += 192) wb[d] = wpb[d];
    }

#define STAGE_T1(LL, BUF) do {                                                 \
    const uint32_t* sh = reinterpret_cast<const uint32_t*>(                    \
        T1hi + ((size_t)(LL) * NN + i) * 2048);                                \
    const uint32_t* sl = reinterpret_cast<const uint32_t*>(                    \
        T1lo + ((size_t)(LL) * NN + i) * 2048);                                \
    uint32_t* dh = reinterpret_cast<uint32_t*>(t1h[BUF]);                      \
    uint32_t* dl = reinterpret_cast<uint32_t*>(t1l[BUF]);                      \
    for (int d = TX; d < 1024; d += 192) {                                     \
        int kk = d >> 5, ee = (d & 31) * 2;                                    \
        int du = ((((kk >> 4) * 2 + (ee >> 5)) * 512 +                         \
                   (((ee >> 3) & 3) * 16 + (kk & 15)) * 8 + (ee & 7)) >> 1);   \
        dh[du] = sh[d]; dl[du] = sl[d];                                        \
    }                                                                          \
} while (0)

#define X_TILE(LL, MT, CUR, SCR) do {                                          \
    shortx8 Bh[2], Bl[2];                                                      \
    _Pragma("unroll") for (int eh = 0; eh < 2; eh++) {                         \
        size_t boff = ((size_t)(6 + (LL)) * NN + (j0w + (MT) * 16 + lr)) * 64  \
                      + eh * 32 + lq * 8;                                      \
        Bh[eh] = *reinterpret_cast<const shortx8*>(hbhi + boff);               \
        Bl[eh] = *reinterpret_cast<const shortx8*>(hblo + boff);               \
    }                                                                          \
    uint32_t* xs = xspill + ((((size_t)blockIdx.x * 3 + w) * 6 + (LL)) * 4     \
                             + (MT)) * 512 + lane * 8;                         \
    _Pragma("unroll") for (int kt = 0; kt < 2; kt++) {                         \
        floatx4 a = (floatx4){0.f, 0.f, 0.f, 0.f};                             \
        _Pragma("unroll") for (int eh = 0; eh < 2; eh++) {                     \
            shortx8 Ah = *reinterpret_cast<const shortx8*>(                    \
                t1h[CUR] + (kt * 2 + eh) * 512 + lane * 8);                    \
            shortx8 Al = *reinterpret_cast<const shortx8*>(                    \
                t1l[CUR] + (kt * 2 + eh) * 512 + lane * 8);                    \
            a = __builtin_amdgcn_mfma_f32_16x16x32_bf16(Ah, Bh[eh], a, 0, 0, 0); \
            a = __builtin_amdgcn_mfma_f32_16x16x32_bf16(Ah, Bl[eh], a, 0, 0, 0); \
            a = __builtin_amdgcn_mfma_f32_16x16x32_bf16(Al, Bh[eh], a, 0, 0, 0); \
        }                                                                      \
        *reinterpret_cast<floatx4*>((SCR) + lr * 36 + kt * 16 + lq * 4) = a;   \
        uint4 uv;                                                              \
        uv.x = packhl(a[0]); uv.y = packhl(a[1]);                              \
        uv.z = packhl(a[2]); uv.w = packhl(a[3]);                              \
        *reinterpret_cast<uint4*>(xs + kt * 4) = uv;                           \
    }                                                                          \
} while (0)

    shortx8 hAh[4], hAl[4];
    float hC[4][2][4], pf[4][2][4], sdr[4][4];
#pragma unroll
    for (int mt = 0; mt < 4; mt++) {
#pragma unroll
        for (int t = 0; t < 8; t++) { hAh[mt][t] = 0; hAl[mt][t] = 0; }
#pragma unroll
        for (int g2 = 0; g2 < 2; g2++)
#pragma unroll
            for (int r = 0; r < 4; r++) { hC[mt][g2][r] = 0.0f; pf[mt][g2][r] = 0.0f; }
#pragma unroll
        for (int r = 0; r < 4; r++) sdr[mt][r] = 0.0f;
    }

    STAGE_T1(0, 0);
    __syncthreads();

    // ================= phase A: GRU + layer attention (MFMA) =================
#pragma unroll 1
    for (int l = 0; l < 6; l++) {
        const int cur = l & 1;
        if (l < 5) STAGE_T1(l + 1, cur ^ 1);
#pragma unroll
        for (int mt = 0; mt < 4; mt++) {
            float* scr = scrw + (mt & 1) * 580;
            X_TILE(l, mt, cur, scr);
            shortx8 xAh, xAl;
            BUILD_AF(xAh, xAl, scr);
            floatx4 aRZ[4], aIN[2], aHN[2];
#pragma unroll
            for (int gt = 0; gt < 4; gt++) {
                floatx4 a = (floatx4){0.f, 0.f, 0.f, 0.f};
                a = __builtin_amdgcn_mfma_f32_16x16x32_bf16(xAh, WF(0, gt), a, 0, 0, 0);
                a = __builtin_amdgcn_mfma_f32_16x16x32_bf16(xAh, WF(3072, gt), a, 0, 0, 0);
                a = __builtin_amdgcn_mfma_f32_16x16x32_bf16(xAl, WF(0, gt), a, 0, 0, 0);
                a = __builtin_amdgcn_mfma_f32_16x16x32_bf16(hAh[mt], WF(6144, gt), a, 0, 0, 0);
                a = __builtin_amdgcn_mfma_f32_16x16x32_bf16(hAh[mt], WF(9216, gt), a, 0, 0, 0);
                a = __builtin_amdgcn_mfma_f32_16x16x32_bf16(hAl[mt], WF(6144, gt), a, 0, 0, 0);
                aRZ[gt] = a;
            }
#pragma unroll
            for (int g2 = 0; g2 < 2; g2++) {
                floatx4 a = (floatx4){0.f, 0.f, 0.f, 0.f};
                a = __builtin_amdgcn_mfma_f32_16x16x32_bf16(xAh, WF(0, 4 + g2), a, 0, 0, 0);
                a = __builtin_amdgcn_mfma_f32_16x16x32_bf16(xAh, WF(3072, 4 + g2), a, 0, 0, 0);
                a = __builtin_amdgcn_mfma_f32_16x16x32_bf16(xAl, WF(0, 4 + g2), a, 0, 0, 0);
                aIN[g2] = a;
                floatx4 b = (floatx4){0.f, 0.f, 0.f, 0.f};
                b = __builtin_amdgcn_mfma_f32_16x16x32_bf16(hAh[mt], WF(6144, 4 + g2), b, 0, 0, 0);
                b = __builtin_amdgcn_mfma_f32_16x16x32_bf16(hAh[mt], WF(9216, 4 + g2), b, 0, 0, 0);
                b = __builtin_amdgcn_mfma_f32_16x16x32_bf16(hAl[mt], WF(6144, 4 + g2), b, 0, 0, 0);
                aHN[g2] = b;
            }
#pragma unroll
            for (int g2 = 0; g2 < 2; g2++)
#pragma unroll
                for (int r = 0; r < 4; r++) {
                    float rg = sigm(aRZ[g2][r] + wb[g2 * 16 + lr]);
                    float zg = sigm(aRZ[2 + g2][r] + wb[32 + g2 * 16 + lr]);
                    float ng = tanhf_(aIN[g2][r] + wb[64 + g2 * 16 + lr]
                                      + rg * (aHN[g2][r] + wb[96 + g2 * 16 + lr]));
                    hC[mt][g2][r] = (1.0f - zg) * ng + zg * hC[mt][g2][r];
                }
#pragma unroll
            for (int g2 = 0; g2 < 2; g2++)
#pragma unroll
                for (int r = 0; r < 4; r++)
                    scr[(4 * lq + r) * 36 + g2 * 16 + lr] = hC[mt][g2][r];
            BUILD_AF(hAh[mt], hAl[mt], scr);
            floatx4 tac[2];
#pragma unroll
            for (int ct = 0; ct < 2; ct++) {
                floatx4 a = (floatx4){0.f, 0.f, 0.f, 0.f};
                a = __builtin_amdgcn_mfma_f32_16x16x32_bf16(hAh[mt], WF(12288, ct), a, 0, 0, 0);
                a = __builtin_amdgcn_mfma_f32_16x16x32_bf16(hAh[mt], WF(13312, ct), a, 0, 0, 0);
                a = __builtin_amdgcn_mfma_f32_16x16x32_bf16(hAl[mt], WF(12288, ct), a, 0, 0, 0);
                tac[ct] = a;
            }
            float rs[4];
#pragma unroll
            for (int r = 0; r < 4; r++)
                rs[r] = tanhf_(tac[0][r] + wb[128 + lr]) * wb[160 + lr]
                      + tanhf_(tac[1][r] + wb[144 + lr]) * wb[176 + lr];
#pragma unroll
            for (int m = 1; m < 16; m <<= 1)
#pragma unroll
                for (int r = 0; r < 4; r++) rs[r] += __shfl_xor(rs[r], m, 64);
#pragma unroll
            for (int r = 0; r < 4; r++) {
                float en = __expf(rs[r]);
                sdr[mt][r] += en;
#pragma unroll
                for (int g2 = 0; g2 < 2; g2++)
                    pf[mt][g2][r] += en * hC[mt][g2][r];
            }
        }
        __syncthreads();
    }

    // ---------------- handoff: pattern -> per-thread, then q -> qk ----------------
    float patt[KD];
    {
#pragma unroll
        for (int mt = 0; mt < 4; mt++) {
            float* scr = scrw + (mt & 1) * 580;
#pragma unroll
            for (int g2 = 0; g2 < 2; g2++)
#pragma unroll
                for (int r = 0; r < 4; r++)
                    scr[(4 * lq + r) * 36 + g2 * 16 + lr] = pf[mt][g2][r];
#pragma unroll
            for (int r = 0; r < 4; r++)
                scr[(4 * lq + r) * 36 + 32] = sdr[mt][r];
            if ((lane >> 4) == mt) {
                float is = 1.0f / scr[(lane & 15) * 36 + 32];
#pragma unroll
                for (int k = 0; k < KD; k++) patt[k] = scr[(lane & 15) * 36 + k] * is;
            }
        }
    }
    float qk[KD], qd;
    {
        float t1r[KD];
#pragma unroll
        for (int c = 0; c < KD; c++) {
            float t = q1b[c];
#pragma unroll
            for (int k = 0; k < KD; k++) t += patt[k] * q1w[k * KD + c];
            t1r[c] = fmaxf(t, 0.0f);
        }
        float q[KD];
#pragma unroll
        for (int c = 0; c < KD; c++) {
            float t = q2b[c];
#pragma unroll
            for (int k = 0; k < KD; k++) t += t1r[k] * q2w[k * KD + c];
            q[c] = t;
        }
        qd = 0.0f;
#pragma unroll
        for (int c = 0; c < KD; c++) qd += q[c] * kb[c];
#pragma unroll
        for (int k = 0; k < KD; k++) {
            float t = 0.0f;
#pragma unroll
            for (int c = 0; c < KD; c++) t += q[c] * kw[k * KD + c];
            qk[k] = t;
        }
    }

    // ================= phase B: scores + context from spilled x =================
    float ctx[KD];
#pragma unroll
    for (int k = 0; k < KD; k++) ctx[k] = 0.0f;
    float s2m = -1e30f, s2d = 0.0f;
#pragma unroll 1
    for (int l = 0; l < 6; l++) {
        float eo = 1.0f, en = 0.0f;
#pragma unroll
        for (int mt = 0; mt < 4; mt++) {
            float* scr = scrw + (mt & 1) * 580;
            const uint32_t* xs = xspill + ((((size_t)blockIdx.x * 3 + w) * 6 + l) * 4
                                           + mt) * 512 + lane * 8;
            uint4 u0 = *reinterpret_cast<const uint4*>(xs);
            uint4 u1 = *reinterpret_cast<const uint4*>(xs + 4);
            floatx4 a0, a1;
            a0[0] = unpackhl(u0.x); a0[1] = unpackhl(u0.y);
            a0[2] = unpackhl(u0.z); a0[3] = unpackhl(u0.w);
            a1[0] = unpackhl(u1.x); a1[1] = unpackhl(u1.y);
            a1[2] = unpackhl(u1.z); a1[3] = unpackhl(u1.w);
            *reinterpret_cast<floatx4*>(scr + lr * 36 + 0 * 16 + lq * 4) = a0;
            *reinterpret_cast<floatx4*>(scr + lr * 36 + 1 * 16 + lq * 4) = a1;
            if ((lane >> 4) == mt) {
                float s = qd;
#pragma unroll
                for (int k = 0; k < KD; k++) s += scr[(lane & 15) * 36 + k] * qk[k];
                s *= 0.17677669529663687f;
                float nm = fmaxf(s2m, s);
                eo = __expf(s2m - nm); en = __expf(s - nm);
                s2d = s2d * eo + en; s2m = nm;
            }
            shortx8 xAh, xAl;
            BUILD_AF(xAh, xAl, scr);
#pragma unroll
            for (int ct = 0; ct < 2; ct++) {
                floatx4 a = (floatx4){0.f, 0.f, 0.f, 0.f};
                a = __builtin_amdgcn_mfma_f32_16x16x32_bf16(xAh, WF(14336, ct), a, 0, 0, 0);
                a = __builtin_amdgcn_mfma_f32_16x16x32_bf16(xAh, WF(15360, ct), a, 0, 0, 0);
                a = __builtin_amdgcn_mfma_f32_16x16x32_bf16(xAl, WF(14336, ct), a, 0, 0, 0);
#pragma unroll
                for (int r = 0; r < 4; r++)
                    scr[(4 * lq + r) * 36 + ct * 16 + lr] = a[r];
            }
            if ((lane >> 4) == mt) {
#pragma unroll
                for (int c = 0; c < KD; c++)
                    ctx[c] = ctx[c] * eo + en * (scr[(lane & 15) * 36 + c] + wb[192 + c]);
            }
        }
    }
    float invd = 1.0f / s2d;
    float* op = out + ((size_t)i * NN + j0w + lane) * KD;
#pragma unroll
    for (int k = 0; k < KD; k += 4) {
        float4 w4;
        w4.x = ctx[k] * invd; w4.y = ctx[k + 1] * invd;
        w4.z = ctx[k + 2] * invd; w4.w = ctx[k + 3] * invd;
        *reinterpret_cast<float4*>(op + k) = w4;
    }
#undef STAGE_T1
#undef X_TILE
}

extern "C" void kernel_launch(void* const* d_in, const int* in_sizes, int n_in,
                              void* d_out, int out_size, void* d_ws, size_t ws_size,
                              hipStream_t stream) {
    const float* f1   = (const float*)d_in[0];
    const float* f2   = (const float*)d_in[1];
    const float* l0w1 = (const float*)d_in[2];
    const float* l0b1 = (const float*)d_in[3];
    const float* l0w2 = (const float*)d_in[4];
    const float* l0b2 = (const float*)d_in[5];
    const float* geps = (const float*)d_in[6];
    const float* gw1  = (const float*)d_in[7];
    const float* gb1  = (const float*)d_in[8];
    const float* gw2  = (const float*)d_in[9];
    const float* gb2  = (const float*)d_in[10];
    const float* gga  = (const float*)d_in[11];
    const float* gbe  = (const float*)d_in[12];
    const float* ged  = (const float*)d_in[13];
    const float* wih  = (const float*)d_in[14];
    const float* whh  = (const float*)d_in[15];
    const float* bih  = (const float*)d_in[16];
    const float* bhh  = (const float*)d_in[17];
    const float* waw  = (const float*)d_in[18];
    const float* wab  = (const float*)d_in[19];
    const float* vat  = (const float*)d_in[20];
    const float* q1w  = (const float*)d_in[21];
    const float* q1b  = (const float*)d_in[22];
    const float* q2w  = (const float*)d_in[23];
    const float* q2b  = (const float*)d_in[24];
    const float* kw   = (const float*)d_in[25];
    const float* kb   = (const float*)d_in[26];
    const float* vw   = (const float*)d_in[27];
    const float* vb   = (const float*)d_in[28];
    const int*   e1   = (const int*)d_in[29];
    const int*   e2   = (const int*)d_in[30];

    // ---- workspace layout ----
    float* C       = (float*)d_ws;                       // 2*NN*NN
    float* Adj     = C + (size_t)2 * NN * NN;            // 2*NN*NN
    float* bnst    = Adj + (size_t)2 * NN * NN;          // 1280
    float* X       = bnst + 1280;                        // 2*NN*33
    float* H       = X + (size_t)2 * NN * 33;            // 2*NN*F
    float* HS      = H + (size_t)2 * NN * F;             // [2][6][NN][F]
    float* wpb     = HS + (size_t)2 * 6 * NN * F;        // 224 (+pad to 256)
    uint16_t* hbhi = (uint16_t*)(wpb + 256);             // [2][6][NN][F]
    uint16_t* hblo = hbhi + (size_t)2 * 6 * NN * F;
    uint16_t* gThi = hblo + (size_t)2 * 6 * NN * F;      // 6*2048*64
    uint16_t* gTlo = gThi + (size_t)6 * 2048 * 64;
    uint16_t* T1hi = gTlo + (size_t)6 * 2048 * 64;       // 6*NN*2048
    uint16_t* T1lo = T1hi + (size_t)6 * NN * 2048;
    uint16_t* wpk  = T1lo + (size_t)6 * NN * 2048;       // 16384
    uint32_t* xspill = (uint32_t*)(wpk + 16384);         // 113 MB
    float* out = (float*)d_out;

    const int GHS = 6 * NN * F;
    const int GH  = NN * F;

    k_zero<<<576, 256, 0, stream>>>(C, 4 * NN * NN + 1280);
    k_build<<<(2 * NE + 255) / 256, 256, 0, stream>>>(e1, e2, C, Adj);
    k_degx<<<dim3(6, 2), 64, 0, stream>>>(f1, f2, Adj, X);
    k_lin0<<<dim3(NN, 2), 64, 0, stream>>>(X, l0w1, l0b1, l0w2, l0b2, HS, hbhi, hblo);
    for (int li = 0; li < 5; li++) {
        const float* hp = (li == 0) ? HS : H;
        int hGs = (li == 0) ? GHS : GH;
        k_gin<<<dim3(NN, 2), 64, 0, stream>>>(C, hp, hGs, gw1, gb1, gw2, gb2,
                                              geps, li, HS + (li + 1) * GH, GHS, bnst);
        k_bnapply<<<dim3(12, 2), 256, 0, stream>>>(HS + (li + 1) * GH, GHS, H, GH,
                                                   gga + li * F, gbe + li * F,
                                                   bnst, li, hbhi, hblo,
                                                   (li + 1) * GH);
    }
    k_gedT2<<<6 * KD, 64, 0, stream>>>(ged, gThi, gTlo);
    k_wprep5<<<1, 256, 0, stream>>>(wih, whh, waw, vw, bih, bhh, wab, vat, vb,
                                    wpk, wpb);
    k_t1m2<<<dim3(16, 3, 6), 256, 0, stream>>>(gThi, gTlo, hbhi, hblo, T1hi, T1lo);
    k_mega15<<<768, 192, 0, stream>>>(T1hi, T1lo, hbhi, hblo, wpk, wpb,
                                      q1w, q1b, q2w, q2b, kw, kb, xspill, out);
}

// Round 19
// 530.770 us; speedup vs baseline: 1.3136x; 1.2836x over previous
//
#include <hip/hip_runtime.h>
#include <stdint.h>

#define NN 384
#define NE 3456
#define NLb 32
#define F 64
#define KD 32

typedef short shortx8 __attribute__((ext_vector_type(8)));
typedef float floatx4 __attribute__((ext_vector_type(4)));

__device__ __forceinline__ float sigm(float v) { return 1.0f / (1.0f + __expf(-v)); }
__device__ __forceinline__ float tanhf_(float v) {
    float x = fminf(fmaxf(v, -15.0f), 15.0f);
    float e = __expf(2.0f * x);
    return (e - 1.0f) / (e + 1.0f);
}
__device__ __forceinline__ uint16_t f2bf(float f) {
    uint32_t u = __float_as_uint(f);
    uint32_t r = (u + 0x7fffu + ((u >> 16) & 1u)) >> 16;
    return (uint16_t)r;
}
__device__ __forceinline__ float bf2f(uint16_t h) {
    return __uint_as_float((uint32_t)h << 16);
}
__device__ __forceinline__ uint32_t packhl(float v) {
    uint16_t h = f2bf(v);
    uint16_t l = f2bf(v - bf2f(h));
    return ((uint32_t)h << 16) | (uint32_t)l;
}
__device__ __forceinline__ float unpackhl(uint32_t u) {
    return __uint_as_float(u & 0xffff0000u) + __uint_as_float(u << 16);
}

__global__ void k_zero(float* p, int n) {
    int i = blockIdx.x * 256 + threadIdx.x;
    int st = gridDim.x * 256;
    for (; i < n; i += st) p[i] = 0.0f;
}

__global__ void k_build(const int* __restrict__ e1, const int* __restrict__ e2,
                        float* __restrict__ C, float* __restrict__ Adj) {
    int t = blockIdx.x * 256 + threadIdx.x;
    if (t >= 2 * NE) return;
    int g = t / NE, e = t % NE;
    const int* ei = g ? e2 : e1;
    int s = ei[e], d = ei[NE + e];
    atomicAdd(&C[(size_t)g * NN * NN + d * NN + s], 1.0f);
    if (e < NE - NN) Adj[(size_t)g * NN * NN + s * NN + d] = 1.0f;
}

__global__ void k_degx(const float* __restrict__ f1, const float* __restrict__ f2,
                       const float* __restrict__ Adj, float* __restrict__ X) {
    int g = blockIdx.y;
    int s = blockIdx.x * 64 + threadIdx.x;
    const float* feats = g ? f2 : f1;
    const float* A = Adj + (size_t)g * NN * NN;
    float* Xg = X + (size_t)g * NN * 33;
    float deg = 0.0f;
    for (int d = 0; d < NN; d++) deg += A[s * NN + d];
    for (int c = 0; c < NLb; c++) Xg[s * 33 + c] = feats[s * NLb + c];
    Xg[s * 33 + 32] = deg;
}

// lin0 row + inline hi/lo bf16 for HS slot 0
__global__ __launch_bounds__(64)
void k_lin0(const float* __restrict__ X, const float* __restrict__ w1,
            const float* __restrict__ b1, const float* __restrict__ w2,
            const float* __restrict__ b2, float* __restrict__ HS,
            uint16_t* __restrict__ hhi, uint16_t* __restrict__ hlo) {
    __shared__ float tl[64];
    int g = blockIdx.y, m = blockIdx.x, n = threadIdx.x;
    const float* Xr = X + (size_t)g * NN * 33 + m * 33;
    float t = b1[n];
#pragma unroll
    for (int k = 0; k < 33; k++) t += Xr[k] * w1[k * F + n];
    t = fmaxf(t, 0.0f);
    tl[n] = t;
    __syncthreads();
    float o = b2[n];
#pragma unroll 4
    for (int k = 0; k < F; k++) o += tl[k] * w2[k * F + n];
    size_t idx = (size_t)g * (6 * NN * F) + m * F + n;
    HS[idx] = o;
    uint16_t hh = f2bf(o);
    hhi[idx] = hh;
    hlo[idx] = f2bf(o - bf2f(hh));
}

// GIN layer row (z agg + MLP) + column-stat atomics for BN
__global__ __launch_bounds__(64)
void k_gin(const float* __restrict__ C, const float* __restrict__ hin, int hGs,
           const float* __restrict__ gw1, const float* __restrict__ gb1,
           const float* __restrict__ gw2, const float* __restrict__ gb2,
           const float* __restrict__ geps, int li,
           float* __restrict__ zout, int oGs, float* __restrict__ stats) {
    __shared__ float zl[64], tl[64];
    int g = blockIdx.y, m = blockIdx.x, n = threadIdx.x;
    const float* Crow = C + (size_t)g * NN * NN + (size_t)m * NN;
    const float* h = hin + (size_t)g * hGs;
    float acc = 0.0f;
#pragma unroll 4
    for (int k = 0; k < NN; k++) acc += Crow[k] * h[k * F + n];
    acc += (1.0f + geps[li]) * h[m * F + n];
    zl[n] = acc;
    __syncthreads();
    const float* W1 = gw1 + (size_t)li * F * F;
    const float* W2 = gw2 + (size_t)li * F * F;
    float t = gb1[li * F + n];
#pragma unroll 4
    for (int k = 0; k < F; k++) t += zl[k] * W1[k * F + n];
    t = fmaxf(t, 0.0f);
    tl[n] = t;
    __syncthreads();
    float o = gb2[li * F + n];
#pragma unroll 4
    for (int k = 0; k < F; k++) o += tl[k] * W2[k * F + n];
    zout[(size_t)g * oGs + m * F + n] = o;
    float* st = stats + li * 256 + g * 128;
    atomicAdd(&st[n], o);
    atomicAdd(&st[64 + n], o * o);
}

// BN apply (batch stats from k_gin atomics) + relu->H + hi/lo bf16 for HS slot
__global__ __launch_bounds__(256)
void k_bnapply(float* __restrict__ hsb, int hsGs, float* __restrict__ hbuf, int hGs,
               const float* __restrict__ gamma, const float* __restrict__ beta,
               const float* __restrict__ stats, int li,
               uint16_t* __restrict__ hhi, uint16_t* __restrict__ hlo, int slotOff) {
    int g = blockIdx.y;
    int base = (blockIdx.x * 256 + threadIdx.x) * 8;
    float* z = hsb + (size_t)g * hsGs;
    float* h = hbuf + (size_t)g * hGs;
    const float* st = stats + li * 256 + g * 128;
    int c0 = base & 63;
#pragma unroll
    for (int q = 0; q < 8; q++) {
        int idx = base + q;
        int c = c0 + q;
        float mu = st[c] * (1.0f / NN);
        float var = st[64 + c] * (1.0f / NN) - mu * mu;
        float is = rsqrtf(var + 1e-5f);
        float zn = (z[idx] - mu) * is * gamma[c] + beta[c];
        z[idx] = zn;
        h[idx] = fmaxf(zn, 0.0f);
        size_t hidx = (size_t)g * (6 * NN * F) + slotOff + idx;
        uint16_t hh = f2bf(zn);
        hhi[hidx] = hh;
        hlo[hidx] = f2bf(zn - bf2f(hh));
    }
}

__global__ __launch_bounds__(64)
void k_gedT2(const float* __restrict__ ged, uint16_t* __restrict__ ghi,
             uint16_t* __restrict__ glo) {
    __shared__ float t[64 * 65];
    int lk = blockIdx.x, lane = threadIdx.x;
    const float* src = ged + (size_t)lk * 4096;
    for (int d = 0; d < 64; d++) t[lane * 65 + d] = src[d * 64 + lane];
    __syncthreads();
    for (int e = 0; e < 64; e++) {
        float v = t[e * 65 + lane];
        uint16_t h = f2bf(v);
        ghi[(size_t)lk * 4096 + e * 64 + lane] = h;
        glo[(size_t)lk * 4096 + e * 64 + lane] = f2bf(v - bf2f(h));
    }
}

// Fragment-linear weight pack (u16) + biases (f32) — verified r11.
__global__ __launch_bounds__(256)
void k_wprep5(const float* __restrict__ wih, const float* __restrict__ whh,
              const float* __restrict__ waw, const float* __restrict__ vw,
              const float* __restrict__ bih, const float* __restrict__ bhh,
              const float* __restrict__ wab, const float* __restrict__ vat,
              const float* __restrict__ vb,
              uint16_t* __restrict__ wpk, float* __restrict__ wpb) {
    int t = threadIdx.x;
    for (int d = t; d < 3072; d += 256) {
        int c = d >> 9, L = (d >> 3) & 63, tt = d & 7;
        int src = (c * 16 + (L & 15)) * 32 + (L >> 4) * 8 + tt;
        float vi = wih[src]; uint16_t hi = f2bf(vi);
        wpk[d] = hi; wpk[3072 + d] = f2bf(vi - bf2f(hi));
        float vh = whh[src]; uint16_t hh = f2bf(vh);
        wpk[6144 + d] = hh; wpk[9216 + d] = f2bf(vh - bf2f(hh));
    }
    for (int d = t; d < 1024; d += 256) {
        int c = d >> 9, L = (d >> 3) & 63, tt = d & 7;
        int row = c * 16 + (L & 15), col = (L >> 4) * 8 + tt;
        float va = waw[col * 32 + row]; uint16_t ha = f2bf(va);
        wpk[12288 + d] = ha; wpk[13312 + d] = f2bf(va - bf2f(ha));
        float vv2 = vw[col * 32 + row]; uint16_t hv = f2bf(vv2);
        wpk[14336 + d] = hv; wpk[15360 + d] = f2bf(vv2 - bf2f(hv));
    }
    if (t < 32) {
        wpb[t]       = bih[t] + bhh[t];
        wpb[32 + t]  = bih[32 + t] + bhh[32 + t];
        wpb[64 + t]  = bih[64 + t];
        wpb[96 + t]  = bhh[64 + t];
        wpb[128 + t] = wab[t];
        wpb[160 + t] = vat[t];
        wpb[192 + t] = vb[t];
    }
}

// T1[l,i,n=k*64+e] hi/lo bf16 = sum_d gedT[l,n,d]*h1[l,i,d]  (verified r3+)
__global__ __launch_bounds__(256)
void k_t1m2(const uint16_t* __restrict__ gThi, const uint16_t* __restrict__ gTlo,
            const uint16_t* __restrict__ hbhi, const uint16_t* __restrict__ hblo,
            uint16_t* __restrict__ T1hi, uint16_t* __restrict__ T1lo) {
    int l = blockIdx.z;
    int w = threadIdx.x >> 6, lane = threadIdx.x & 63;
    int nb = blockIdx.x * 128 + (w >> 1) * 64;
    int ib = blockIdx.y * 128 + (w & 1) * 64;
    int lr = lane & 15, lq = lane >> 4;
    const uint16_t* gah = gThi + (size_t)l * 2048 * 64;
    const uint16_t* gal = gTlo + (size_t)l * 2048 * 64;
    const uint16_t* gbh = hbhi + (size_t)l * NN * F;
    const uint16_t* gbl = hblo + (size_t)l * NN * F;
    shortx8 Ah[4][2], Al[4][2];
#pragma unroll
    for (int s = 0; s < 4; s++)
#pragma unroll
        for (int ks = 0; ks < 2; ks++) {
            size_t off = (size_t)(nb + s * 16 + lr) * 64 + ks * 32 + lq * 8;
            Ah[s][ks] = *reinterpret_cast<const shortx8*>(gah + off);
            Al[s][ks] = *reinterpret_cast<const shortx8*>(gal + off);
        }
#pragma unroll
    for (int si = 0; si < 4; si++) {
        shortx8 Bh[2], Bl[2];
#pragma unroll
        for (int ks = 0; ks < 2; ks++) {
            size_t off = (size_t)(ib + si * 16 + lr) * 64 + ks * 32 + lq * 8;
            Bh[ks] = *reinterpret_cast<const shortx8*>(gbh + off);
            Bl[ks] = *reinterpret_cast<const shortx8*>(gbl + off);
        }
#pragma unroll
        for (int sn = 0; sn < 4; sn++) {
            floatx4 a = (floatx4){0.f, 0.f, 0.f, 0.f};
#pragma unroll
            for (int ks = 0; ks < 2; ks++) {
                a = __builtin_amdgcn_mfma_f32_16x16x32_bf16(Ah[sn][ks], Bh[ks], a, 0, 0, 0);
                a = __builtin_amdgcn_mfma_f32_16x16x32_bf16(Ah[sn][ks], Bl[ks], a, 0, 0, 0);
                a = __builtin_amdgcn_mfma_f32_16x16x32_bf16(Al[sn][ks], Bh[ks], a, 0, 0, 0);
            }
            size_t addr = ((size_t)l * NN + (ib + si * 16 + lr)) * 2048 + (nb + sn * 16 + lq * 4);
            uint2 hv, lv;
            uint16_t h0 = f2bf(a[0]), h1 = f2bf(a[1]), h2 = f2bf(a[2]), h3 = f2bf(a[3]);
            hv.x = (uint32_t)h0 | ((uint32_t)h1 << 16);
            hv.y = (uint32_t)h2 | ((uint32_t)h3 << 16);
            uint16_t l0 = f2bf(a[0] - bf2f(h0)), l1 = f2bf(a[1] - bf2f(h1));
            uint16_t l2 = f2bf(a[2] - bf2f(h2)), l3 = f2bf(a[3] - bf2f(h3));
            lv.x = (uint32_t)l0 | ((uint32_t)l1 << 16);
            lv.y = (uint32_t)l2 | ((uint32_t)l3 << 16);
            *reinterpret_cast<uint2*>(T1hi + addr) = hv;
            *reinterpret_cast<uint2*>(T1lo + addr) = lv;
        }
    }
}

#define WF(OFF, CC) (*reinterpret_cast<const shortx8*>(wl + (OFF) + (CC) * 512 + lane * 8))

// build hi/lo bf16 A-frag from mt-scratch SCR (rows=lr, k=lq*8+t, stride 36)
#define BUILD_AF(H8, L8, SCR) do {                                             \
    _Pragma("unroll") for (int t = 0; t < 8; t++) {                            \
        float fv = (SCR)[lr * 36 + lq * 8 + t];                                \
        uint16_t hc = f2bf(fv);                                                \
        H8[t] = (short)hc;                                                     \
        L8[t] = (short)f2bf(fv - bf2f(hc));                                    \
    }                                                                          \
} while (0)

// mega17 = verified mega15 reshaped to 9-wave blocks, grid 256 (exactly 1
// block/CU, zero tail): block covers 576 consecutive pairs spanning 2 i-rows;
// T1 staging holds BOTH tiles (mega8-verified dual-tile select); per-wave
// logic byte-identical to mega15.
__global__ __launch_bounds__(576, 1)
void k_mega17(const uint16_t* __restrict__ T1hi, const uint16_t* __restrict__ T1lo,
              const uint16_t* __restrict__ hbhi, const uint16_t* __restrict__ hblo,
              const uint16_t* __restrict__ wpk, const float* __restrict__ wpb,
              const float* __restrict__ q1w, const float* __restrict__ q1b,
              const float* __restrict__ q2w, const float* __restrict__ q2b,
              const float* __restrict__ kw, const float* __restrict__ kb,
              uint32_t* __restrict__ xspill, float* __restrict__ out) {
    __shared__ uint16_t wl[16384];
    __shared__ float wb[224];
    __shared__ uint16_t t1h[2][2][2048], t1l[2][2][2048];   // [dbuf][it][...]
    __shared__ float scr_all[9 * 2 * 580];
    const int TX = threadIdx.x;
    const int w = TX >> 6, lane = TX & 63, lr = lane & 15, lq = lane >> 4;
    const int p0 = blockIdx.x * 576;
    const int pw = p0 + w * 64;
    const int i  = pw / NN;          // wave-uniform (NN % 64 == 0)
    const int j0w = pw - i * NN;
    const int i0 = p0 / NN;
    const int myit = i - i0;         // 0 or 1
    float* scrw = scr_all + w * 2 * 580;

    {
        uint32_t* wl32 = reinterpret_cast<uint32_t*>(wl);
        const uint32_t* src32 = reinterpret_cast<const uint32_t*>(wpk);
        for (int d = TX; d < 8192; d += 576) wl32[d] = src32[d];
        for (int d = TX; d < 224; d += 576) wb[d] = wpb[d];
    }

    // stage BOTH i-tiles of layer LL into dbuf BUF (no barriers inside)
#define STAGE_T1(LL, BUF) do {                                                 \
    uint32_t* dh = reinterpret_cast<uint32_t*>(t1h[BUF]);                      \
    uint32_t* dl = reinterpret_cast<uint32_t*>(t1l[BUF]);                      \
    for (int d = TX; d < 2048; d += 576) {                                     \
        int it = d >> 10, dd = d & 1023;                                       \
        const uint32_t* sh = reinterpret_cast<const uint32_t*>(                \
            T1hi + ((size_t)(LL) * NN + i0 + it) * 2048);                      \
        const uint32_t* sl = reinterpret_cast<const uint32_t*>(                \
            T1lo + ((size_t)(LL) * NN + i0 + it) * 2048);                      \
        int kk = dd >> 5, ee = (dd & 31) * 2;                                  \
        int du = ((((kk >> 4) * 2 + (ee >> 5)) * 512 +                         \
                   (((ee >> 3) & 3) * 16 + (kk & 15)) * 8 + (ee & 7)) >> 1);   \
        dh[it * 1024 + du] = sh[dd]; dl[it * 1024 + du] = sl[dd];              \
    }                                                                          \
} while (0)

#define X_TILE(LL, MT, CUR, SCR) do {                                          \
    shortx8 Bh[2], Bl[2];                                                      \
    _Pragma("unroll") for (int eh = 0; eh < 2; eh++) {                         \
        size_t boff = ((size_t)(6 + (LL)) * NN + (j0w + (MT) * 16 + lr)) * 64  \
                      + eh * 32 + lq * 8;                                      \
        Bh[eh] = *reinterpret_cast<const shortx8*>(hbhi + boff);               \
        Bl[eh] = *reinterpret_cast<const shortx8*>(hblo + boff);               \
    }                                                                          \
    uint32_t* xs = xspill + ((((size_t)blockIdx.x * 9 + w) * 6 + (LL)) * 4     \
                             + (MT)) * 512 + lane * 8;                         \
    _Pragma("unroll") for (int kt = 0; kt < 2; kt++) {                         \
        floatx4 a = (floatx4){0.f, 0.f, 0.f, 0.f};                             \
        _Pragma("unroll") for (int eh = 0; eh < 2; eh++) {                     \
            shortx8 Ah = *reinterpret_cast<const shortx8*>(                    \
                t1h[CUR][myit] + (kt * 2 + eh) * 512 + lane * 8);              \
            shortx8 Al = *reinterpret_cast<const shortx8*>(                    \
                t1l[CUR][myit] + (kt * 2 + eh) * 512 + lane * 8);              \
            a = __builtin_amdgcn_mfma_f32_16x16x32_bf16(Ah, Bh[eh], a, 0, 0, 0); \
            a = __builtin_amdgcn_mfma_f32_16x16x32_bf16(Ah, Bl[eh], a, 0, 0, 0); \
            a = __builtin_amdgcn_mfma_f32_16x16x32_bf16(Al, Bh[eh], a, 0, 0, 0); \
        }                                                                      \
        *reinterpret_cast<floatx4*>((SCR) + lr * 36 + kt * 16 + lq * 4) = a;   \
        uint4 uv;                                                              \
        uv.x = packhl(a[0]); uv.y = packhl(a[1]);                              \
        uv.z = packhl(a[2]); uv.w = packhl(a[3]);                              \
        *reinterpret_cast<uint4*>(xs + kt * 4) = uv;                           \
    }                                                                          \
} while (0)

    shortx8 hAh[4], hAl[4];
    float hC[4][2][4], pf[4][2][4], sdr[4][4];
#pragma unroll
    for (int mt = 0; mt < 4; mt++) {
#pragma unroll
        for (int t = 0; t < 8; t++) { hAh[mt][t] = 0; hAl[mt][t] = 0; }
#pragma unroll
        for (int g2 = 0; g2 < 2; g2++)
#pragma unroll
            for (int r = 0; r < 4; r++) { hC[mt][g2][r] = 0.0f; pf[mt][g2][r] = 0.0f; }
#pragma unroll
        for (int r = 0; r < 4; r++) sdr[mt][r] = 0.0f;
    }

    STAGE_T1(0, 0);
    __syncthreads();

    // ================= phase A: GRU + layer attention (MFMA) =================
#pragma unroll 1
    for (int l = 0; l < 6; l++) {
        const int cur = l & 1;
        if (l < 5) STAGE_T1(l + 1, cur ^ 1);
#pragma unroll
        for (int mt = 0; mt < 4; mt++) {
            float* scr = scrw + (mt & 1) * 580;
            X_TILE(l, mt, cur, scr);
            shortx8 xAh, xAl;
            BUILD_AF(xAh, xAl, scr);
            floatx4 aRZ[4], aIN[2], aHN[2];
#pragma unroll
            for (int gt = 0; gt < 4; gt++) {
                floatx4 a = (floatx4){0.f, 0.f, 0.f, 0.f};
                a = __builtin_amdgcn_mfma_f32_16x16x32_bf16(xAh, WF(0, gt), a, 0, 0, 0);
                a = __builtin_amdgcn_mfma_f32_16x16x32_bf16(xAh, WF(3072, gt), a, 0, 0, 0);
                a = __builtin_amdgcn_mfma_f32_16x16x32_bf16(xAl, WF(0, gt), a, 0, 0, 0);
                a = __builtin_amdgcn_mfma_f32_16x16x32_bf16(hAh[mt], WF(6144, gt), a, 0, 0, 0);
                a = __builtin_amdgcn_mfma_f32_16x16x32_bf16(hAh[mt], WF(9216, gt), a, 0, 0, 0);
                a = __builtin_amdgcn_mfma_f32_16x16x32_bf16(hAl[mt], WF(6144, gt), a, 0, 0, 0);
                aRZ[gt] = a;
            }
#pragma unroll
            for (int g2 = 0; g2 < 2; g2++) {
                floatx4 a = (floatx4){0.f, 0.f, 0.f, 0.f};
                a = __builtin_amdgcn_mfma_f32_16x16x32_bf16(xAh, WF(0, 4 + g2), a, 0, 0, 0);
                a = __builtin_amdgcn_mfma_f32_16x16x32_bf16(xAh, WF(3072, 4 + g2), a, 0, 0, 0);
                a = __builtin_amdgcn_mfma_f32_16x16x32_bf16(xAl, WF(0, 4 + g2), a, 0, 0, 0);
                aIN[g2] = a;
                floatx4 b = (floatx4){0.f, 0.f, 0.f, 0.f};
                b = __builtin_amdgcn_mfma_f32_16x16x32_bf16(hAh[mt], WF(6144, 4 + g2), b, 0, 0, 0);
                b = __builtin_amdgcn_mfma_f32_16x16x32_bf16(hAh[mt], WF(9216, 4 + g2), b, 0, 0, 0);
                b = __builtin_amdgcn_mfma_f32_16x16x32_bf16(hAl[mt], WF(6144, 4 + g2), b, 0, 0, 0);
                aHN[g2] = b;
            }
#pragma unroll
            for (int g2 = 0; g2 < 2; g2++)
#pragma unroll
                for (int r = 0; r < 4; r++) {
                    float rg = sigm(aRZ[g2][r] + wb[g2 * 16 + lr]);
                    float zg = sigm(aRZ[2 + g2][r] + wb[32 + g2 * 16 + lr]);
                    float ng = tanhf_(aIN[g2][r] + wb[64 + g2 * 16 + lr]
                                      + rg * (aHN[g2][r] + wb[96 + g2 * 16 + lr]));
                    hC[mt][g2][r] = (1.0f - zg) * ng + zg * hC[mt][g2][r];
                }
#pragma unroll
            for (int g2 = 0; g2 < 2; g2++)
#pragma unroll
                for (int r = 0; r < 4; r++)
                    scr[(4 * lq + r) * 36 + g2 * 16 + lr] = hC[mt][g2][r];
            BUILD_AF(hAh[mt], hAl[mt], scr);
            floatx4 tac[2];
#pragma unroll
            for (int ct = 0; ct < 2; ct++) {
                floatx4 a = (floatx4){0.f, 0.f, 0.f, 0.f};
                a = __builtin_amdgcn_mfma_f32_16x16x32_bf16(hAh[mt], WF(12288, ct), a, 0, 0, 0);
                a = __builtin_amdgcn_mfma_f32_16x16x32_bf16(hAh[mt], WF(13312, ct), a, 0, 0, 0);
                a = __builtin_amdgcn_mfma_f32_16x16x32_bf16(hAl[mt], WF(12288, ct), a, 0, 0, 0);
                tac[ct] = a;
            }
            float rs[4];
#pragma unroll
            for (int r = 0; r < 4; r++)
                rs[r] = tanhf_(tac[0][r] + wb[128 + lr]) * wb[160 + lr]
                      + tanhf_(tac[1][r] + wb[144 + lr]) * wb[176 + lr];
#pragma unroll
            for (int m = 1; m < 16; m <<= 1)
#pragma unroll
                for (int r = 0; r < 4; r++) rs[r] += __shfl_xor(rs[r], m, 64);
#pragma unroll
            for (int r = 0; r < 4; r++) {
                float en = __expf(rs[r]);
                sdr[mt][r] += en;
#pragma unroll
                for (int g2 = 0; g2 < 2; g2++)
                    pf[mt][g2][r] += en * hC[mt][g2][r];
            }
        }
        __syncthreads();
    }

    // ---------------- handoff: pattern -> per-thread, then q -> qk ----------------
    float patt[KD];
    {
#pragma unroll
        for (int mt = 0; mt < 4; mt++) {
            float* scr = scrw + (mt & 1) * 580;
#pragma unroll
            for (int g2 = 0; g2 < 2; g2++)
#pragma unroll
                for (int r = 0; r < 4; r++)
                    scr[(4 * lq + r) * 36 + g2 * 16 + lr] = pf[mt][g2][r];
#pragma unroll
            for (int r = 0; r < 4; r++)
                scr[(4 * lq + r) * 36 + 32] = sdr[mt][r];
            if ((lane >> 4) == mt) {
                float is = 1.0f / scr[(lane & 15) * 36 + 32];
#pragma unroll
                for (int k = 0; k < KD; k++) patt[k] = scr[(lane & 15) * 36 + k] * is;
            }
        }
    }
    float qk[KD], qd;
    {
        float t1r[KD];
#pragma unroll
        for (int c = 0; c < KD; c++) {
            float t = q1b[c];
#pragma unroll
            for (int k = 0; k < KD; k++) t += patt[k] * q1w[k * KD + c];
            t1r[c] = fmaxf(t, 0.0f);
        }
        float q[KD];
#pragma unroll
        for (int c = 0; c < KD; c++) {
            float t = q2b[c];
#pragma unroll
            for (int k = 0; k < KD; k++) t += t1r[k] * q2w[k * KD + c];
            q[c] = t;
        }
        qd = 0.0f;
#pragma unroll
        for (int c = 0; c < KD; c++) qd += q[c] * kb[c];
#pragma unroll
        for (int k = 0; k < KD; k++) {
            float t = 0.0f;
#pragma unroll
            for (int c = 0; c < KD; c++) t += q[c] * kw[k * KD + c];
            qk[k] = t;
        }
    }

    // ================= phase B: scores + context from spilled x =================
    float ctx[KD];
#pragma unroll
    for (int k = 0; k < KD; k++) ctx[k] = 0.0f;
    float s2m = -1e30f, s2d = 0.0f;
#pragma unroll 1
    for (int l = 0; l < 6; l++) {
        float eo = 1.0f, en = 0.0f;
#pragma unroll
        for (int mt = 0; mt < 4; mt++) {
            float* scr = scrw + (mt & 1) * 580;
            const uint32_t* xs = xspill + ((((size_t)blockIdx.x * 9 + w) * 6 + l) * 4
                                           + mt) * 512 + lane * 8;
            uint4 u0 = *reinterpret_cast<const uint4*>(xs);
            uint4 u1 = *reinterpret_cast<const uint4*>(xs + 4);
            floatx4 a0, a1;
            a0[0] = unpackhl(u0.x); a0[1] = unpackhl(u0.y);
            a0[2] = unpackhl(u0.z); a0[3] = unpackhl(u0.w);
            a1[0] = unpackhl(u1.x); a1[1] = unpackhl(u1.y);
            a1[2] = unpackhl(u1.z); a1[3] = unpackhl(u1.w);
            *reinterpret_cast<floatx4*>(scr + lr * 36 + 0 * 16 + lq * 4) = a0;
            *reinterpret_cast<floatx4*>(scr + lr * 36 + 1 * 16 + lq * 4) = a1;
            if ((lane >> 4) == mt) {
                float s = qd;
#pragma unroll
                for (int k = 0; k < KD; k++) s += scr[(lane & 15) * 36 + k] * qk[k];
                s *= 0.17677669529663687f;
                float nm = fmaxf(s2m, s);
                eo = __expf(s2m - nm); en = __expf(s - nm);
                s2d = s2d * eo + en; s2m = nm;
            }
            shortx8 xAh, xAl;
            BUILD_AF(xAh, xAl, scr);
#pragma unroll
            for (int ct = 0; ct < 2; ct++) {
                floatx4 a = (floatx4){0.f, 0.f, 0.f, 0.f};
                a = __builtin_amdgcn_mfma_f32_16x16x32_bf16(xAh, WF(14336, ct), a, 0, 0, 0);
                a = __builtin_amdgcn_mfma_f32_16x16x32_bf16(xAh, WF(15360, ct), a, 0, 0, 0);
                a = __builtin_amdgcn_mfma_f32_16x16x32_bf16(xAl, WF(14336, ct), a, 0, 0, 0);
#pragma unroll
                for (int r = 0; r < 4; r++)
                    scr[(4 * lq + r) * 36 + ct * 16 + lr] = a[r];
            }
            if ((lane >> 4) == mt) {
#pragma unroll
                for (int c = 0; c < KD; c++)
                    ctx[c] = ctx[c] * eo + en * (scr[(lane & 15) * 36 + c] + wb[192 + c]);
            }
        }
    }
    float invd = 1.0f / s2d;
    float* op = out + ((size_t)i * NN + j0w + lane) * KD;
#pragma unroll
    for (int k = 0; k < KD; k += 4) {
        float4 w4;
        w4.x = ctx[k] * invd; w4.y = ctx[k + 1] * invd;
        w4.z = ctx[k + 2] * invd; w4.w = ctx[k + 3] * invd;
        *reinterpret_cast<float4*>(op + k) = w4;
    }
#undef STAGE_T1
#undef X_TILE
}

extern "C" void kernel_launch(void* const* d_in, const int* in_sizes, int n_in,
                              void* d_out, int out_size, void* d_ws, size_t ws_size,
                              hipStream_t stream) {
    const float* f1   = (const float*)d_in[0];
    const float* f2   = (const float*)d_in[1];
    const float* l0w1 = (const float*)d_in[2];
    const float* l0b1 = (const float*)d_in[3];
    const float* l0w2 = (const float*)d_in[4];
    const float* l0b2 = (const float*)d_in[5];
    const float* geps = (const float*)d_in[6];
    const float* gw1  = (const float*)d_in[7];
    const float* gb1  = (const float*)d_in[8];
    const float* gw2  = (const float*)d_in[9];
    const float* gb2  = (const float*)d_in[10];
    const float* gga  = (const float*)d_in[11];
    const float* gbe  = (const float*)d_in[12];
    const float* ged  = (const float*)d_in[13];
    const float* wih  = (const float*)d_in[14];
    const float* whh  = (const float*)d_in[15];
    const float* bih  = (const float*)d_in[16];
    const float* bhh  = (const float*)d_in[17];
    const float* waw  = (const float*)d_in[18];
    const float* wab  = (const float*)d_in[19];
    const float* vat  = (const float*)d_in[20];
    const float* q1w  = (const float*)d_in[21];
    const float* q1b  = (const float*)d_in[22];
    const float* q2w  = (const float*)d_in[23];
    const float* q2b  = (const float*)d_in[24];
    const float* kw   = (const float*)d_in[25];
    const float* kb   = (const float*)d_in[26];
    const float* vw   = (const float*)d_in[27];
    const float* vb   = (const float*)d_in[28];
    const int*   e1   = (const int*)d_in[29];
    const int*   e2   = (const int*)d_in[30];

    // ---- workspace layout ----
    float* C       = (float*)d_ws;                       // 2*NN*NN
    float* Adj     = C + (size_t)2 * NN * NN;            // 2*NN*NN
    float* bnst    = Adj + (size_t)2 * NN * NN;          // 1280
    float* X       = bnst + 1280;                        // 2*NN*33
    float* H       = X + (size_t)2 * NN * 33;            // 2*NN*F
    float* HS      = H + (size_t)2 * NN * F;             // [2][6][NN][F]
    float* wpb     = HS + (size_t)2 * 6 * NN * F;        // 224 (+pad to 256)
    uint16_t* hbhi = (uint16_t*)(wpb + 256);             // [2][6][NN][F]
    uint16_t* hblo = hbhi + (size_t)2 * 6 * NN * F;
    uint16_t* gThi = hblo + (size_t)2 * 6 * NN * F;      // 6*2048*64
    uint16_t* gTlo = gThi + (size_t)6 * 2048 * 64;
    uint16_t* T1hi = gTlo + (size_t)6 * 2048 * 64;       // 6*NN*2048
    uint16_t* T1lo = T1hi + (size_t)6 * NN * 2048;
    uint16_t* wpk  = T1lo + (size_t)6 * NN * 2048;       // 16384
    uint32_t* xspill = (uint32_t*)(wpk + 16384);         // 256*9*6*4*512 u32 = 113 MB
    float* out = (float*)d_out;

    const int GHS = 6 * NN * F;
    const int GH  = NN * F;

    k_zero<<<576, 256, 0, stream>>>(C, 4 * NN * NN + 1280);
    k_build<<<(2 * NE + 255) / 256, 256, 0, stream>>>(e1, e2, C, Adj);
    k_degx<<<dim3(6, 2), 64, 0, stream>>>(f1, f2, Adj, X);
    k_lin0<<<dim3(NN, 2), 64, 0, stream>>>(X, l0w1, l0b1, l0w2, l0b2, HS, hbhi, hblo);
    for (int li = 0; li < 5; li++) {
        const float* hp = (li == 0) ? HS : H;
        int hGs = (li == 0) ? GHS : GH;
        k_gin<<<dim3(NN, 2), 64, 0, stream>>>(C, hp, hGs, gw1, gb1, gw2, gb2,
                                              geps, li, HS + (li + 1) * GH, GHS, bnst);
        k_bnapply<<<dim3(12, 2), 256, 0, stream>>>(HS + (li + 1) * GH, GHS, H, GH,
                                                   gga + li * F, gbe + li * F,
                                                   bnst, li, hbhi, hblo,
                                                   (li + 1) * GH);
    }
    k_gedT2<<<6 * KD, 64, 0, stream>>>(ged, gThi, gTlo);
    k_wprep5<<<1, 256, 0, stream>>>(wih, whh, waw, vw, bih, bhh, wab, vat, vb,
                                    wpk, wpb);
    k_t1m2<<<dim3(16, 3, 6), 256, 0, stream>>>(gThi, gTlo, hbhi, hblo, T1hi, T1lo);
    k_mega17<<<256, 576, 0, stream>>>(T1hi, T1lo, hbhi, hblo, wpk, wpb,
                                      q1w, q1b, q2w, q2b, kw, kb, xspill, out);
}

// Round 20
// 529.395 us; speedup vs baseline: 1.3171x; 1.0026x over previous
//
#include <hip/hip_runtime.h>
#include <stdint.h>

#define NN 384
#define NE 3456
#define NLb 32
#define F 64
#define KD 32

typedef short shortx8 __attribute__((ext_vector_type(8)));
typedef float floatx4 __attribute__((ext_vector_type(4)));

__device__ __forceinline__ float sigm(float v) { return 1.0f / (1.0f + __expf(-v)); }
__device__ __forceinline__ float tanhf_(float v) {
    float x = fminf(fmaxf(v, -15.0f), 15.0f);
    float e = __expf(2.0f * x);
    return (e - 1.0f) / (e + 1.0f);
}
__device__ __forceinline__ uint16_t f2bf(float f) {
    uint32_t u = __float_as_uint(f);
    uint32_t r = (u + 0x7fffu + ((u >> 16) & 1u)) >> 16;
    return (uint16_t)r;
}
__device__ __forceinline__ float bf2f(uint16_t h) {
    return __uint_as_float((uint32_t)h << 16);
}
__device__ __forceinline__ uint32_t packhl(float v) {
    uint16_t h = f2bf(v);
    uint16_t l = f2bf(v - bf2f(h));
    return ((uint32_t)h << 16) | (uint32_t)l;
}
__device__ __forceinline__ float unpackhl(uint32_t u) {
    return __uint_as_float(u & 0xffff0000u) + __uint_as_float(u << 16);
}

__global__ void k_zero(float* p, int n) {
    int i = blockIdx.x * 256 + threadIdx.x;
    int st = gridDim.x * 256;
    for (; i < n; i += st) p[i] = 0.0f;
}

__global__ void k_build(const int* __restrict__ e1, const int* __restrict__ e2,
                        float* __restrict__ C, float* __restrict__ Adj) {
    int t = blockIdx.x * 256 + threadIdx.x;
    if (t >= 2 * NE) return;
    int g = t / NE, e = t % NE;
    const int* ei = g ? e2 : e1;
    int s = ei[e], d = ei[NE + e];
    atomicAdd(&C[(size_t)g * NN * NN + d * NN + s], 1.0f);
    if (e < NE - NN) Adj[(size_t)g * NN * NN + s * NN + d] = 1.0f;
}

__global__ void k_degx(const float* __restrict__ f1, const float* __restrict__ f2,
                       const float* __restrict__ Adj, float* __restrict__ X) {
    int g = blockIdx.y;
    int s = blockIdx.x * 64 + threadIdx.x;
    const float* feats = g ? f2 : f1;
    const float* A = Adj + (size_t)g * NN * NN;
    float* Xg = X + (size_t)g * NN * 33;
    float deg = 0.0f;
    for (int d = 0; d < NN; d++) deg += A[s * NN + d];
    for (int c = 0; c < NLb; c++) Xg[s * 33 + c] = feats[s * NLb + c];
    Xg[s * 33 + 32] = deg;
}

// lin0 row + inline hi/lo bf16 for HS slot 0
__global__ __launch_bounds__(64)
void k_lin0(const float* __restrict__ X, const float* __restrict__ w1,
            const float* __restrict__ b1, const float* __restrict__ w2,
            const float* __restrict__ b2, float* __restrict__ HS,
            uint16_t* __restrict__ hhi, uint16_t* __restrict__ hlo) {
    __shared__ float tl[64];
    int g = blockIdx.y, m = blockIdx.x, n = threadIdx.x;
    const float* Xr = X + (size_t)g * NN * 33 + m * 33;
    float t = b1[n];
#pragma unroll
    for (int k = 0; k < 33; k++) t += Xr[k] * w1[k * F + n];
    t = fmaxf(t, 0.0f);
    tl[n] = t;
    __syncthreads();
    float o = b2[n];
#pragma unroll 4
    for (int k = 0; k < F; k++) o += tl[k] * w2[k * F + n];
    size_t idx = (size_t)g * (6 * NN * F) + m * F + n;
    HS[idx] = o;
    uint16_t hh = f2bf(o);
    hhi[idx] = hh;
    hlo[idx] = f2bf(o - bf2f(hh));
}

// GIN layer row (z agg + MLP) + column-stat atomics for BN
__global__ __launch_bounds__(64)
void k_gin(const float* __restrict__ C, const float* __restrict__ hin, int hGs,
           const float* __restrict__ gw1, const float* __restrict__ gb1,
           const float* __restrict__ gw2, const float* __restrict__ gb2,
           const float* __restrict__ geps, int li,
           float* __restrict__ zout, int oGs, float* __restrict__ stats) {
    __shared__ float zl[64], tl[64];
    int g = blockIdx.y, m = blockIdx.x, n = threadIdx.x;
    const float* Crow = C + (size_t)g * NN * NN + (size_t)m * NN;
    const float* h = hin + (size_t)g * hGs;
    float acc = 0.0f;
#pragma unroll 4
    for (int k = 0; k < NN; k++) acc += Crow[k] * h[k * F + n];
    acc += (1.0f + geps[li]) * h[m * F + n];
    zl[n] = acc;
    __syncthreads();
    const float* W1 = gw1 + (size_t)li * F * F;
    const float* W2 = gw2 + (size_t)li * F * F;
    float t = gb1[li * F + n];
#pragma unroll 4
    for (int k = 0; k < F; k++) t += zl[k] * W1[k * F + n];
    t = fmaxf(t, 0.0f);
    tl[n] = t;
    __syncthreads();
    float o = gb2[li * F + n];
#pragma unroll 4
    for (int k = 0; k < F; k++) o += tl[k] * W2[k * F + n];
    zout[(size_t)g * oGs + m * F + n] = o;
    float* st = stats + li * 256 + g * 128;
    atomicAdd(&st[n], o);
    atomicAdd(&st[64 + n], o * o);
}

// BN apply (batch stats from k_gin atomics) + relu->H + hi/lo bf16 for HS slot
__global__ __launch_bounds__(256)
void k_bnapply(float* __restrict__ hsb, int hsGs, float* __restrict__ hbuf, int hGs,
               const float* __restrict__ gamma, const float* __restrict__ beta,
               const float* __restrict__ stats, int li,
               uint16_t* __restrict__ hhi, uint16_t* __restrict__ hlo, int slotOff) {
    int g = blockIdx.y;
    int base = (blockIdx.x * 256 + threadIdx.x) * 8;
    float* z = hsb + (size_t)g * hsGs;
    float* h = hbuf + (size_t)g * hGs;
    const float* st = stats + li * 256 + g * 128;
    int c0 = base & 63;
#pragma unroll
    for (int q = 0; q < 8; q++) {
        int idx = base + q;
        int c = c0 + q;
        float mu = st[c] * (1.0f / NN);
        float var = st[64 + c] * (1.0f / NN) - mu * mu;
        float is = rsqrtf(var + 1e-5f);
        float zn = (z[idx] - mu) * is * gamma[c] + beta[c];
        z[idx] = zn;
        h[idx] = fmaxf(zn, 0.0f);
        size_t hidx = (size_t)g * (6 * NN * F) + slotOff + idx;
        uint16_t hh = f2bf(zn);
        hhi[hidx] = hh;
        hlo[hidx] = f2bf(zn - bf2f(hh));
    }
}

__global__ __launch_bounds__(64)
void k_gedT2(const float* __restrict__ ged, uint16_t* __restrict__ ghi,
             uint16_t* __restrict__ glo) {
    __shared__ float t[64 * 65];
    int lk = blockIdx.x, lane = threadIdx.x;
    const float* src = ged + (size_t)lk * 4096;
    for (int d = 0; d < 64; d++) t[lane * 65 + d] = src[d * 64 + lane];
    __syncthreads();
    for (int e = 0; e < 64; e++) {
        float v = t[e * 65 + lane];
        uint16_t h = f2bf(v);
        ghi[(size_t)lk * 4096 + e * 64 + lane] = h;
        glo[(size_t)lk * 4096 + e * 64 + lane] = f2bf(v - bf2f(h));
    }
}

// Fragment-linear weight pack (u16) + biases (f32) — verified r11.
__global__ __launch_bounds__(256)
void k_wprep5(const float* __restrict__ wih, const float* __restrict__ whh,
              const float* __restrict__ waw, const float* __restrict__ vw,
              const float* __restrict__ bih, const float* __restrict__ bhh,
              const float* __restrict__ wab, const float* __restrict__ vat,
              const float* __restrict__ vb,
              uint16_t* __restrict__ wpk, float* __restrict__ wpb) {
    int t = threadIdx.x;
    for (int d = t; d < 3072; d += 256) {
        int c = d >> 9, L = (d >> 3) & 63, tt = d & 7;
        int src = (c * 16 + (L & 15)) * 32 + (L >> 4) * 8 + tt;
        float vi = wih[src]; uint16_t hi = f2bf(vi);
        wpk[d] = hi; wpk[3072 + d] = f2bf(vi - bf2f(hi));
        float vh = whh[src]; uint16_t hh = f2bf(vh);
        wpk[6144 + d] = hh; wpk[9216 + d] = f2bf(vh - bf2f(hh));
    }
    for (int d = t; d < 1024; d += 256) {
        int c = d >> 9, L = (d >> 3) & 63, tt = d & 7;
        int row = c * 16 + (L & 15), col = (L >> 4) * 8 + tt;
        float va = waw[col * 32 + row]; uint16_t ha = f2bf(va);
        wpk[12288 + d] = ha; wpk[13312 + d] = f2bf(va - bf2f(ha));
        float vv2 = vw[col * 32 + row]; uint16_t hv = f2bf(vv2);
        wpk[14336 + d] = hv; wpk[15360 + d] = f2bf(vv2 - bf2f(hv));
    }
    if (t < 32) {
        wpb[t]       = bih[t] + bhh[t];
        wpb[32 + t]  = bih[32 + t] + bhh[32 + t];
        wpb[64 + t]  = bih[64 + t];
        wpb[96 + t]  = bhh[64 + t];
        wpb[128 + t] = wab[t];
        wpb[160 + t] = vat[t];
        wpb[192 + t] = vb[t];
    }
}

// T1[l,i,n=k*64+e] hi/lo bf16 = sum_d gedT[l,n,d]*h1[l,i,d]  (verified r3+)
__global__ __launch_bounds__(256)
void k_t1m2(const uint16_t* __restrict__ gThi, const uint16_t* __restrict__ gTlo,
            const uint16_t* __restrict__ hbhi, const uint16_t* __restrict__ hblo,
            uint16_t* __restrict__ T1hi, uint16_t* __restrict__ T1lo) {
    int l = blockIdx.z;
    int w = threadIdx.x >> 6, lane = threadIdx.x & 63;
    int nb = blockIdx.x * 128 + (w >> 1) * 64;
    int ib = blockIdx.y * 128 + (w & 1) * 64;
    int lr = lane & 15, lq = lane >> 4;
    const uint16_t* gah = gThi + (size_t)l * 2048 * 64;
    const uint16_t* gal = gTlo + (size_t)l * 2048 * 64;
    const uint16_t* gbh = hbhi + (size_t)l * NN * F;
    const uint16_t* gbl = hblo + (size_t)l * NN * F;
    shortx8 Ah[4][2], Al[4][2];
#pragma unroll
    for (int s = 0; s < 4; s++)
#pragma unroll
        for (int ks = 0; ks < 2; ks++) {
            size_t off = (size_t)(nb + s * 16 + lr) * 64 + ks * 32 + lq * 8;
            Ah[s][ks] = *reinterpret_cast<const shortx8*>(gah + off);
            Al[s][ks] = *reinterpret_cast<const shortx8*>(gal + off);
        }
#pragma unroll
    for (int si = 0; si < 4; si++) {
        shortx8 Bh[2], Bl[2];
#pragma unroll
        for (int ks = 0; ks < 2; ks++) {
            size_t off = (size_t)(ib + si * 16 + lr) * 64 + ks * 32 + lq * 8;
            Bh[ks] = *reinterpret_cast<const shortx8*>(gbh + off);
            Bl[ks] = *reinterpret_cast<const shortx8*>(gbl + off);
        }
#pragma unroll
        for (int sn = 0; sn < 4; sn++) {
            floatx4 a = (floatx4){0.f, 0.f, 0.f, 0.f};
#pragma unroll
            for (int ks = 0; ks < 2; ks++) {
                a = __builtin_amdgcn_mfma_f32_16x16x32_bf16(Ah[sn][ks], Bh[ks], a, 0, 0, 0);
                a = __builtin_amdgcn_mfma_f32_16x16x32_bf16(Ah[sn][ks], Bl[ks], a, 0, 0, 0);
                a = __builtin_amdgcn_mfma_f32_16x16x32_bf16(Al[sn][ks], Bh[ks], a, 0, 0, 0);
            }
            size_t addr = ((size_t)l * NN + (ib + si * 16 + lr)) * 2048 + (nb + sn * 16 + lq * 4);
            uint2 hv, lv;
            uint16_t h0 = f2bf(a[0]), h1 = f2bf(a[1]), h2 = f2bf(a[2]), h3 = f2bf(a[3]);
            hv.x = (uint32_t)h0 | ((uint32_t)h1 << 16);
            hv.y = (uint32_t)h2 | ((uint32_t)h3 << 16);
            uint16_t l0 = f2bf(a[0] - bf2f(h0)), l1 = f2bf(a[1] - bf2f(h1));
            uint16_t l2 = f2bf(a[2] - bf2f(h2)), l3 = f2bf(a[3] - bf2f(h3));
            lv.x = (uint32_t)l0 | ((uint32_t)l1 << 16);
            lv.y = (uint32_t)l2 | ((uint32_t)l3 << 16);
            *reinterpret_cast<uint2*>(T1hi + addr) = hv;
            *reinterpret_cast<uint2*>(T1lo + addr) = lv;
        }
    }
}

#define WF(OFF, CC) (*reinterpret_cast<const shortx8*>(wl + (OFF) + (CC) * 512 + lane * 8))

// build hi/lo bf16 A-frag from mt-scratch SCR (rows=lr, k=lq*8+t, stride 36)
#define BUILD_AF(H8, L8, SCR) do {                                             \
    _Pragma("unroll") for (int t = 0; t < 8; t++) {                            \
        float fv = (SCR)[lr * 36 + lq * 8 + t];                                \
        uint16_t hc = f2bf(fv);                                                \
        H8[t] = (short)hc;                                                     \
        L8[t] = (short)f2bf(fv - bf2f(hc));                                    \
    }                                                                          \
} while (0)

// mega17 (verified r19) + phase-B layer loop reversed (l=5..0): consumes the
// most recently written (cache-hottest) xspill layers first. Online softmax
// over layers is order-invariant.
__global__ __launch_bounds__(576, 1)
void k_mega17(const uint16_t* __restrict__ T1hi, const uint16_t* __restrict__ T1lo,
              const uint16_t* __restrict__ hbhi, const uint16_t* __restrict__ hblo,
              const uint16_t* __restrict__ wpk, const float* __restrict__ wpb,
              const float* __restrict__ q1w, const float* __restrict__ q1b,
              const float* __restrict__ q2w, const float* __restrict__ q2b,
              const float* __restrict__ kw, const float* __restrict__ kb,
              uint32_t* __restrict__ xspill, float* __restrict__ out) {
    __shared__ uint16_t wl[16384];
    __shared__ float wb[224];
    __shared__ uint16_t t1h[2][2][2048], t1l[2][2][2048];   // [dbuf][it][...]
    __shared__ float scr_all[9 * 2 * 580];
    const int TX = threadIdx.x;
    const int w = TX >> 6, lane = TX & 63, lr = lane & 15, lq = lane >> 4;
    const int p0 = blockIdx.x * 576;
    const int pw = p0 + w * 64;
    const int i  = pw / NN;          // wave-uniform (NN % 64 == 0)
    const int j0w = pw - i * NN;
    const int i0 = p0 / NN;
    const int myit = i - i0;         // 0 or 1
    float* scrw = scr_all + w * 2 * 580;

    {
        uint32_t* wl32 = reinterpret_cast<uint32_t*>(wl);
        const uint32_t* src32 = reinterpret_cast<const uint32_t*>(wpk);
        for (int d = TX; d < 8192; d += 576) wl32[d] = src32[d];
        for (int d = TX; d < 224; d += 576) wb[d] = wpb[d];
    }

    // stage BOTH i-tiles of layer LL into dbuf BUF (no barriers inside)
#define STAGE_T1(LL, BUF) do {                                                 \
    uint32_t* dh = reinterpret_cast<uint32_t*>(t1h[BUF]);                      \
    uint32_t* dl = reinterpret_cast<uint32_t*>(t1l[BUF]);                      \
    for (int d = TX; d < 2048; d += 576) {                                     \
        int it = d >> 10, dd = d & 1023;                                       \
        const uint32_t* sh = reinterpret_cast<const uint32_t*>(                \
            T1hi + ((size_t)(LL) * NN + i0 + it) * 2048);                      \
        const uint32_t* sl = reinterpret_cast<const uint32_t*>(                \
            T1lo + ((size_t)(LL) * NN + i0 + it) * 2048);                      \
        int kk = dd >> 5, ee = (dd & 31) * 2;                                  \
        int du = ((((kk >> 4) * 2 + (ee >> 5)) * 512 +                         \
                   (((ee >> 3) & 3) * 16 + (kk & 15)) * 8 + (ee & 7)) >> 1);   \
        dh[it * 1024 + du] = sh[dd]; dl[it * 1024 + du] = sl[dd];              \
    }                                                                          \
} while (0)

#define X_TILE(LL, MT, CUR, SCR) do {                                          \
    shortx8 Bh[2], Bl[2];                                                      \
    _Pragma("unroll") for (int eh = 0; eh < 2; eh++) {                         \
        size_t boff = ((size_t)(6 + (LL)) * NN + (j0w + (MT) * 16 + lr)) * 64  \
                      + eh * 32 + lq * 8;                                      \
        Bh[eh] = *reinterpret_cast<const shortx8*>(hbhi + boff);               \
        Bl[eh] = *reinterpret_cast<const shortx8*>(hblo + boff);               \
    }                                                                          \
    uint32_t* xs = xspill + ((((size_t)blockIdx.x * 9 + w) * 6 + (LL)) * 4     \
                             + (MT)) * 512 + lane * 8;                         \
    _Pragma("unroll") for (int kt = 0; kt < 2; kt++) {                         \
        floatx4 a = (floatx4){0.f, 0.f, 0.f, 0.f};                             \
        _Pragma("unroll") for (int eh = 0; eh < 2; eh++) {                     \
            shortx8 Ah = *reinterpret_cast<const shortx8*>(                    \
                t1h[CUR][myit] + (kt * 2 + eh) * 512 + lane * 8);              \
            shortx8 Al = *reinterpret_cast<const shortx8*>(                    \
                t1l[CUR][myit] + (kt * 2 + eh) * 512 + lane * 8);              \
            a = __builtin_amdgcn_mfma_f32_16x16x32_bf16(Ah, Bh[eh], a, 0, 0, 0); \
            a = __builtin_amdgcn_mfma_f32_16x16x32_bf16(Ah, Bl[eh], a, 0, 0, 0); \
            a = __builtin_amdgcn_mfma_f32_16x16x32_bf16(Al, Bh[eh], a, 0, 0, 0); \
        }                                                                      \
        *reinterpret_cast<floatx4*>((SCR) + lr * 36 + kt * 16 + lq * 4) = a;   \
        uint4 uv;                                                              \
        uv.x = packhl(a[0]); uv.y = packhl(a[1]);                              \
        uv.z = packhl(a[2]); uv.w = packhl(a[3]);                              \
        *reinterpret_cast<uint4*>(xs + kt * 4) = uv;                           \
    }                                                                          \
} while (0)

    shortx8 hAh[4], hAl[4];
    float hC[4][2][4], pf[4][2][4], sdr[4][4];
#pragma unroll
    for (int mt = 0; mt < 4; mt++) {
#pragma unroll
        for (int t = 0; t < 8; t++) { hAh[mt][t] = 0; hAl[mt][t] = 0; }
#pragma unroll
        for (int g2 = 0; g2 < 2; g2++)
#pragma unroll
            for (int r = 0; r < 4; r++) { hC[mt][g2][r] = 0.0f; pf[mt][g2][r] = 0.0f; }
#pragma unroll
        for (int r = 0; r < 4; r++) sdr[mt][r] = 0.0f;
    }

    STAGE_T1(0, 0);
    __syncthreads();

    // ================= phase A: GRU + layer attention (MFMA) =================
#pragma unroll 1
    for (int l = 0; l < 6; l++) {
        const int cur = l & 1;
        if (l < 5) STAGE_T1(l + 1, cur ^ 1);
#pragma unroll
        for (int mt = 0; mt < 4; mt++) {
            float* scr = scrw + (mt & 1) * 580;
            X_TILE(l, mt, cur, scr);
            shortx8 xAh, xAl;
            BUILD_AF(xAh, xAl, scr);
            floatx4 aRZ[4], aIN[2], aHN[2];
#pragma unroll
            for (int gt = 0; gt < 4; gt++) {
                floatx4 a = (floatx4){0.f, 0.f, 0.f, 0.f};
                a = __builtin_amdgcn_mfma_f32_16x16x32_bf16(xAh, WF(0, gt), a, 0, 0, 0);
                a = __builtin_amdgcn_mfma_f32_16x16x32_bf16(xAh, WF(3072, gt), a, 0, 0, 0);
                a = __builtin_amdgcn_mfma_f32_16x16x32_bf16(xAl, WF(0, gt), a, 0, 0, 0);
                a = __builtin_amdgcn_mfma_f32_16x16x32_bf16(hAh[mt], WF(6144, gt), a, 0, 0, 0);
                a = __builtin_amdgcn_mfma_f32_16x16x32_bf16(hAh[mt], WF(9216, gt), a, 0, 0, 0);
                a = __builtin_amdgcn_mfma_f32_16x16x32_bf16(hAl[mt], WF(6144, gt), a, 0, 0, 0);
                aRZ[gt] = a;
            }
#pragma unroll
            for (int g2 = 0; g2 < 2; g2++) {
                floatx4 a = (floatx4){0.f, 0.f, 0.f, 0.f};
                a = __builtin_amdgcn_mfma_f32_16x16x32_bf16(xAh, WF(0, 4 + g2), a, 0, 0, 0);
                a = __builtin_amdgcn_mfma_f32_16x16x32_bf16(xAh, WF(3072, 4 + g2), a, 0, 0, 0);
                a = __builtin_amdgcn_mfma_f32_16x16x32_bf16(xAl, WF(0, 4 + g2), a, 0, 0, 0);
                aIN[g2] = a;
                floatx4 b = (floatx4){0.f, 0.f, 0.f, 0.f};
                b = __builtin_amdgcn_mfma_f32_16x16x32_bf16(hAh[mt], WF(6144, 4 + g2), b, 0, 0, 0);
                b = __builtin_amdgcn_mfma_f32_16x16x32_bf16(hAh[mt], WF(9216, 4 + g2), b, 0, 0, 0);
                b = __builtin_amdgcn_mfma_f32_16x16x32_bf16(hAl[mt], WF(6144, 4 + g2), b, 0, 0, 0);
                aHN[g2] = b;
            }
#pragma unroll
            for (int g2 = 0; g2 < 2; g2++)
#pragma unroll
                for (int r = 0; r < 4; r++) {
                    float rg = sigm(aRZ[g2][r] + wb[g2 * 16 + lr]);
                    float zg = sigm(aRZ[2 + g2][r] + wb[32 + g2 * 16 + lr]);
                    float ng = tanhf_(aIN[g2][r] + wb[64 + g2 * 16 + lr]
                                      + rg * (aHN[g2][r] + wb[96 + g2 * 16 + lr]));
                    hC[mt][g2][r] = (1.0f - zg) * ng + zg * hC[mt][g2][r];
                }
#pragma unroll
            for (int g2 = 0; g2 < 2; g2++)
#pragma unroll
                for (int r = 0; r < 4; r++)
                    scr[(4 * lq + r) * 36 + g2 * 16 + lr] = hC[mt][g2][r];
            BUILD_AF(hAh[mt], hAl[mt], scr);
            floatx4 tac[2];
#pragma unroll
            for (int ct = 0; ct < 2; ct++) {
                floatx4 a = (floatx4){0.f, 0.f, 0.f, 0.f};
                a = __builtin_amdgcn_mfma_f32_16x16x32_bf16(hAh[mt], WF(12288, ct), a, 0, 0, 0);
                a = __builtin_amdgcn_mfma_f32_16x16x32_bf16(hAh[mt], WF(13312, ct), a, 0, 0, 0);
                a = __builtin_amdgcn_mfma_f32_16x16x32_bf16(hAl[mt], WF(12288, ct), a, 0, 0, 0);
                tac[ct] = a;
            }
            float rs[4];
#pragma unroll
            for (int r = 0; r < 4; r++)
                rs[r] = tanhf_(tac[0][r] + wb[128 + lr]) * wb[160 + lr]
                      + tanhf_(tac[1][r] + wb[144 + lr]) * wb[176 + lr];
#pragma unroll
            for (int m = 1; m < 16; m <<= 1)
#pragma unroll
                for (int r = 0; r < 4; r++) rs[r] += __shfl_xor(rs[r], m, 64);
#pragma unroll
            for (int r = 0; r < 4; r++) {
                float en = __expf(rs[r]);
                sdr[mt][r] += en;
#pragma unroll
                for (int g2 = 0; g2 < 2; g2++)
                    pf[mt][g2][r] += en * hC[mt][g2][r];
            }
        }
        __syncthreads();
    }

    // ---------------- handoff: pattern -> per-thread, then q -> qk ----------------
    float patt[KD];
    {
#pragma unroll
        for (int mt = 0; mt < 4; mt++) {
            float* scr = scrw + (mt & 1) * 580;
#pragma unroll
            for (int g2 = 0; g2 < 2; g2++)
#pragma unroll
                for (int r = 0; r < 4; r++)
                    scr[(4 * lq + r) * 36 + g2 * 16 + lr] = pf[mt][g2][r];
#pragma unroll
            for (int r = 0; r < 4; r++)
                scr[(4 * lq + r) * 36 + 32] = sdr[mt][r];
            if ((lane >> 4) == mt) {
                float is = 1.0f / scr[(lane & 15) * 36 + 32];
#pragma unroll
                for (int k = 0; k < KD; k++) patt[k] = scr[(lane & 15) * 36 + k] * is;
            }
        }
    }
    float qk[KD], qd;
    {
        float t1r[KD];
#pragma unroll
        for (int c = 0; c < KD; c++) {
            float t = q1b[c];
#pragma unroll
            for (int k = 0; k < KD; k++) t += patt[k] * q1w[k * KD + c];
            t1r[c] = fmaxf(t, 0.0f);
        }
        float q[KD];
#pragma unroll
        for (int c = 0; c < KD; c++) {
            float t = q2b[c];
#pragma unroll
            for (int k = 0; k < KD; k++) t += t1r[k] * q2w[k * KD + c];
            q[c] = t;
        }
        qd = 0.0f;
#pragma unroll
        for (int c = 0; c < KD; c++) qd += q[c] * kb[c];
#pragma unroll
        for (int k = 0; k < KD; k++) {
            float t = 0.0f;
#pragma unroll
            for (int c = 0; c < KD; c++) t += q[c] * kw[k * KD + c];
            qk[k] = t;
        }
    }

    // ===== phase B: scores + context from spilled x (reverse layer order:
    // most recently written xspill layers are cache-hottest) =====
    float ctx[KD];
#pragma unroll
    for (int k = 0; k < KD; k++) ctx[k] = 0.0f;
    float s2m = -1e30f, s2d = 0.0f;
#pragma unroll 1
    for (int l = 5; l >= 0; l--) {
        float eo = 1.0f, en = 0.0f;
#pragma unroll
        for (int mt = 0; mt < 4; mt++) {
            float* scr = scrw + (mt & 1) * 580;
            const uint32_t* xs = xspill + ((((size_t)blockIdx.x * 9 + w) * 6 + l) * 4
                                           + mt) * 512 + lane * 8;
            uint4 u0 = *reinterpret_cast<const uint4*>(xs);
            uint4 u1 = *reinterpret_cast<const uint4*>(xs + 4);
            floatx4 a0, a1;
            a0[0] = unpackhl(u0.x); a0[1] = unpackhl(u0.y);
            a0[2] = unpackhl(u0.z); a0[3] = unpackhl(u0.w);
            a1[0] = unpackhl(u1.x); a1[1] = unpackhl(u1.y);
            a1[2] = unpackhl(u1.z); a1[3] = unpackhl(u1.w);
            *reinterpret_cast<floatx4*>(scr + lr * 36 + 0 * 16 + lq * 4) = a0;
            *reinterpret_cast<floatx4*>(scr + lr * 36 + 1 * 16 + lq * 4) = a1;
            if ((lane >> 4) == mt) {
                float s = qd;
#pragma unroll
                for (int k = 0; k < KD; k++) s += scr[(lane & 15) * 36 + k] * qk[k];
                s *= 0.17677669529663687f;
                float nm = fmaxf(s2m, s);
                eo = __expf(s2m - nm); en = __expf(s - nm);
                s2d = s2d * eo + en; s2m = nm;
            }
            shortx8 xAh, xAl;
            BUILD_AF(xAh, xAl, scr);
#pragma unroll
            for (int ct = 0; ct < 2; ct++) {
                floatx4 a = (floatx4){0.f, 0.f, 0.f, 0.f};
                a = __builtin_amdgcn_mfma_f32_16x16x32_bf16(xAh, WF(14336, ct), a, 0, 0, 0);
                a = __builtin_amdgcn_mfma_f32_16x16x32_bf16(xAh, WF(15360, ct), a, 0, 0, 0);
                a = __builtin_amdgcn_mfma_f32_16x16x32_bf16(xAl, WF(14336, ct), a, 0, 0, 0);
#pragma unroll
                for (int r = 0; r < 4; r++)
                    scr[(4 * lq + r) * 36 + ct * 16 + lr] = a[r];
            }
            if ((lane >> 4) == mt) {
#pragma unroll
                for (int c = 0; c < KD; c++)
                    ctx[c] = ctx[c] * eo + en * (scr[(lane & 15) * 36 + c] + wb[192 + c]);
            }
        }
    }
    float invd = 1.0f / s2d;
    float* op = out + ((size_t)i * NN + j0w + lane) * KD;
#pragma unroll
    for (int k = 0; k < KD; k += 4) {
        float4 w4;
        w4.x = ctx[k] * invd; w4.y = ctx[k + 1] * invd;
        w4.z = ctx[k + 2] * invd; w4.w = ctx[k + 3] * invd;
        *reinterpret_cast<float4*>(op + k) = w4;
    }
#undef STAGE_T1
#undef X_TILE
}

extern "C" void kernel_launch(void* const* d_in, const int* in_sizes, int n_in,
                              void* d_out, int out_size, void* d_ws, size_t ws_size,
                              hipStream_t stream) {
    const float* f1   = (const float*)d_in[0];
    const float* f2   = (const float*)d_in[1];
    const float* l0w1 = (const float*)d_in[2];
    const float* l0b1 = (const float*)d_in[3];
    const float* l0w2 = (const float*)d_in[4];
    const float* l0b2 = (const float*)d_in[5];
    const float* geps = (const float*)d_in[6];
    const float* gw1  = (const float*)d_in[7];
    const float* gb1  = (const float*)d_in[8];
    const float* gw2  = (const float*)d_in[9];
    const float* gb2  = (const float*)d_in[10];
    const float* gga  = (const float*)d_in[11];
    const float* gbe  = (const float*)d_in[12];
    const float* ged  = (const float*)d_in[13];
    const float* wih  = (const float*)d_in[14];
    const float* whh  = (const float*)d_in[15];
    const float* bih  = (const float*)d_in[16];
    const float* bhh  = (const float*)d_in[17];
    const float* waw  = (const float*)d_in[18];
    const float* wab  = (const float*)d_in[19];
    const float* vat  = (const float*)d_in[20];
    const float* q1w  = (const float*)d_in[21];
    const float* q1b  = (const float*)d_in[22];
    const float* q2w  = (const float*)d_in[23];
    const float* q2b  = (const float*)d_in[24];
    const float* kw   = (const float*)d_in[25];
    const float* kb   = (const float*)d_in[26];
    const float* vw   = (const float*)d_in[27];
    const float* vb   = (const float*)d_in[28];
    const int*   e1   = (const int*)d_in[29];
    const int*   e2   = (const int*)d_in[30];

    // ---- workspace layout ----
    float* C       = (float*)d_ws;                       // 2*NN*NN
    float* Adj     = C + (size_t)2 * NN * NN;            // 2*NN*NN
    float* bnst    = Adj + (size_t)2 * NN * NN;          // 1280
    float* X       = bnst + 1280;                        // 2*NN*33
    float* H       = X + (size_t)2 * NN * 33;            // 2*NN*F
    float* HS      = H + (size_t)2 * NN * F;             // [2][6][NN][F]
    float* wpb     = HS + (size_t)2 * 6 * NN * F;        // 224 (+pad to 256)
    uint16_t* hbhi = (uint16_t*)(wpb + 256);             // [2][6][NN][F]
    uint16_t* hblo = hbhi + (size_t)2 * 6 * NN * F;
    uint16_t* gThi = hblo + (size_t)2 * 6 * NN * F;      // 6*2048*64
    uint16_t* gTlo = gThi + (size_t)6 * 2048 * 64;
    uint16_t* T1hi = gTlo + (size_t)6 * 2048 * 64;       // 6*NN*2048
    uint16_t* T1lo = T1hi + (size_t)6 * NN * 2048;
    uint16_t* wpk  = T1lo + (size_t)6 * NN * 2048;       // 16384
    uint32_t* xspill = (uint32_t*)(wpk + 16384);         // 256*9*6*4*512 u32 = 113 MB
    float* out = (float*)d_out;

    const int GHS = 6 * NN * F;
    const int GH  = NN * F;

    k_zero<<<576, 256, 0, stream>>>(C, 4 * NN * NN + 1280);
    k_build<<<(2 * NE + 255) / 256, 256, 0, stream>>>(e1, e2, C, Adj);
    k_degx<<<dim3(6, 2), 64, 0, stream>>>(f1, f2, Adj, X);
    k_lin0<<<dim3(NN, 2), 64, 0, stream>>>(X, l0w1, l0b1, l0w2, l0b2, HS, hbhi, hblo);
    for (int li = 0; li < 5; li++) {
        const float* hp = (li == 0) ? HS : H;
        int hGs = (li == 0) ? GHS : GH;
        k_gin<<<dim3(NN, 2), 64, 0, stream>>>(C, hp, hGs, gw1, gb1, gw2, gb2,
                                              geps, li, HS + (li + 1) * GH, GHS, bnst);
        k_bnapply<<<dim3(12, 2), 256, 0, stream>>>(HS + (li + 1) * GH, GHS, H, GH,
                                                   gga + li * F, gbe + li * F,
                                                   bnst, li, hbhi, hblo,
                                                   (li + 1) * GH);
    }
    k_gedT2<<<6 * KD, 64, 0, stream>>>(ged, gThi, gTlo);
    k_wprep5<<<1, 256, 0, stream>>>(wih, whh, waw, vw, bih, bhh, wab, vat, vb,
                                    wpk, wpb);
    k_t1m2<<<dim3(16, 3, 6), 256, 0, stream>>>(gThi, gTlo, hbhi, hblo, T1hi, T1lo);
    k_mega17<<<256, 576, 0, stream>>>(T1hi, T1lo, hbhi, hblo, wpk, wpb,
                                      q1w, q1b, q2w, q2b, kw, kb, xspill, out);
}